// Round 2
// baseline (907.880 us; speedup 1.0000x reference)
//
#include <hip/hip_runtime.h>
#include <cstdint>
#include <cstddef>

#define BN_EPS 1e-5f

constexpr int NN = 50000;
constexpr int NE = 800000;

// ---------------- CSR build (edge_index arrives as int32: harness converts int64 -> int) ----
__global__ void count_deg_kernel(const int* __restrict__ ei, int* __restrict__ deg, int E) {
    int e = blockIdx.x * blockDim.x + threadIdx.x;
    if (e >= E) return;
    int d = ei[E + e];
    if ((unsigned)d < (unsigned)NN) atomicAdd(&deg[d], 1);
}

__global__ __launch_bounds__(1024) void scan_kernel(int* __restrict__ deg_cursor,
                                                    int* __restrict__ row_ptr, int n) {
    __shared__ int lds[1024];
    int t = threadIdx.x;
    int CH = (n + 1023) >> 10;
    int base = t * CH;
    int s = 0;
    for (int i = 0; i < CH; i++) { int idx = base + i; if (idx < n) s += deg_cursor[idx]; }
    lds[t] = s;
    __syncthreads();
    for (int off = 1; off < 1024; off <<= 1) {
        int v = (t >= off) ? lds[t - off] : 0;
        __syncthreads();
        lds[t] += v;
        __syncthreads();
    }
    int run = (t == 0) ? 0 : lds[t - 1];
    for (int i = 0; i < CH; i++) {
        int idx = base + i;
        if (idx < n) {
            int d = deg_cursor[idx];
            row_ptr[idx] = run;
            deg_cursor[idx] = run;   // cursor re-init for fill pass
            run += d;
        }
    }
    if (t == 1023) row_ptr[n] = lds[1023];
}

__global__ void fill_csr_kernel(const int* __restrict__ ei, const float* __restrict__ ew,
                                int* __restrict__ cursor, int* __restrict__ csr_src,
                                float* __restrict__ csr_w, int E) {
    int e = blockIdx.x * blockDim.x + threadIdx.x;
    if (e >= E) return;
    int d = ei[E + e];
    int s = ei[e];
    if ((unsigned)d >= (unsigned)NN || (unsigned)s >= (unsigned)NN) return;
    int pos = atomicAdd(&cursor[d], 1);
    if (pos < E) { csr_src[pos] = s; csr_w[pos] = ew[e]; }
}

// ---------------- pull-based aggregation: out[n] = x[n] + sum_e w_e * x[src_e] ----------------
template <int C>
__global__ __launch_bounds__(256) void aggregate_kernel(
    const float* __restrict__ x, const int* __restrict__ row_ptr,
    const int* __restrict__ csr_src, const float* __restrict__ csr_w,
    float* __restrict__ out, int n) {
    int node = blockIdx.x * 4 + (threadIdx.x >> 6);
    if (node >= n) return;
    int lane = threadIdx.x & 63;
    int beg = row_ptr[node], end = row_ptr[node + 1];
    if constexpr (C == 128) {
        int col = lane * 2;
        float2 acc = *(const float2*)(x + (size_t)node * C + col);
        for (int e = beg; e < end; ++e) {
            int s = csr_src[e]; float w = csr_w[e];
            float2 v = *(const float2*)(x + (size_t)s * C + col);
            acc.x = fmaf(w, v.x, acc.x); acc.y = fmaf(w, v.y, acc.y);
        }
        *(float2*)(out + (size_t)node * C + col) = acc;
    } else if constexpr (C == 256) {
        int col = lane * 4;
        float4 acc = *(const float4*)(x + (size_t)node * C + col);
        for (int e = beg; e < end; ++e) {
            int s = csr_src[e]; float w = csr_w[e];
            float4 v = *(const float4*)(x + (size_t)s * C + col);
            acc.x = fmaf(w, v.x, acc.x); acc.y = fmaf(w, v.y, acc.y);
            acc.z = fmaf(w, v.z, acc.z); acc.w = fmaf(w, v.w, acc.w);
        }
        *(float4*)(out + (size_t)node * C + col) = acc;
    } else {  // C == 40
        if (lane < 10) {
            int col = lane * 4;
            float4 acc = *(const float4*)(x + (size_t)node * C + col);
            for (int e = beg; e < end; ++e) {
                int s = csr_src[e]; float w = csr_w[e];
                float4 v = *(const float4*)(x + (size_t)s * C + col);
                acc.x = fmaf(w, v.x, acc.x); acc.y = fmaf(w, v.y, acc.y);
                acc.z = fmaf(w, v.z, acc.z); acc.w = fmaf(w, v.w, acc.w);
            }
            *(float4*)(out + (size_t)node * C + col) = acc;
        }
    }
}

// ---------------- fp32 GEMM, C = epilogue(A @ B) ----------------
// EPI: 0 = none (no bias), 1 = bias+relu, 2 = bias+BN(eval)+relu
template <int BM, int BN, int BK, int TM, int TN, int EPI>
__global__ __launch_bounds__(256) void gemm_kernel(
    const float* __restrict__ A, const float* __restrict__ B, float* __restrict__ C,
    int M, int K, int LDB, int LDC, int NSTORE,
    const float* __restrict__ bias,
    const float* __restrict__ bng, const float* __restrict__ bnb,
    const float* __restrict__ bnm, const float* __restrict__ bnv) {
    static_assert((BM / TM) * (BN / TN) == 256, "256 threads");
    static_assert(BK == 16, "loader assumes BK=16");
    __shared__ float As[BK][BM + 4];  // A^T tile
    __shared__ float Bs[BK][BN + 4];
    const int tid = threadIdx.x;
    const int NX = BN / TN;
    const int tx = tid % NX, ty = tid / NX;
    const int m0 = blockIdx.x * BM, n0 = blockIdx.y * BN;

    float acc[TM][TN];
#pragma unroll
    for (int i = 0; i < TM; i++)
#pragma unroll
        for (int j = 0; j < TN; j++) acc[i][j] = 0.f;

    for (int k0 = 0; k0 < K; k0 += BK) {
#pragma unroll
        for (int i = 0; i < (BM * (BK / 4)) / 256; i++) {
            int t = tid + i * 256;
            int kg = t & 3;
            int row = t >> 2;
            int rowg = m0 + row; if (rowg > M - 1) rowg = M - 1;
            float4 v = *(const float4*)(A + (size_t)rowg * K + k0 + kg * 4);
            As[kg * 4 + 0][row] = v.x; As[kg * 4 + 1][row] = v.y;
            As[kg * 4 + 2][row] = v.z; As[kg * 4 + 3][row] = v.w;
        }
#pragma unroll
        for (int i = 0; i < (BK * (BN / 4)) / 256; i++) {
            int t = tid + i * 256;
            int c4 = t % (BN / 4);
            int kr = t / (BN / 4);
            float4 v = *(const float4*)(B + (size_t)(k0 + kr) * LDB + n0 + c4 * 4);
            *(float4*)(&Bs[kr][c4 * 4]) = v;
        }
        __syncthreads();
#pragma unroll
        for (int kk = 0; kk < BK; kk++) {
            float a[TM], b[TN];
#pragma unroll
            for (int i = 0; i < TM / 4; i++) {
                float4 v = *(const float4*)(&As[kk][ty * TM + i * 4]);
                a[i * 4] = v.x; a[i * 4 + 1] = v.y; a[i * 4 + 2] = v.z; a[i * 4 + 3] = v.w;
            }
#pragma unroll
            for (int j = 0; j < TN / 4; j++) {
                float4 v = *(const float4*)(&Bs[kk][tx * TN + j * 4]);
                b[j * 4] = v.x; b[j * 4 + 1] = v.y; b[j * 4 + 2] = v.z; b[j * 4 + 3] = v.w;
            }
#pragma unroll
            for (int i = 0; i < TM; i++)
#pragma unroll
                for (int j = 0; j < TN; j++) acc[i][j] = fmaf(a[i], b[j], acc[i][j]);
        }
        __syncthreads();
    }

    // epilogue
#pragma unroll
    for (int j4 = 0; j4 < TN / 4; j4++) {
        int cb = n0 + tx * TN + j4 * 4;
        if (cb >= NSTORE) continue;  // NSTORE % 4 == 0 -> group fully in or out
        float bb[4] = {0.f, 0.f, 0.f, 0.f}, sc[4], sh[4];
        if constexpr (EPI >= 1) {
#pragma unroll
            for (int j = 0; j < 4; j++) bb[j] = bias[cb + j];
        }
        if constexpr (EPI == 2) {
#pragma unroll
            for (int j = 0; j < 4; j++) {
                float s = bng[cb + j] * rsqrtf(bnv[cb + j] + BN_EPS);
                sc[j] = s;
                sh[j] = bnb[cb + j] - bnm[cb + j] * s;
            }
        }
#pragma unroll
        for (int i = 0; i < TM; i++) {
            int r = m0 + ty * TM + i;
            if (r >= M) continue;
            float vals[4];
#pragma unroll
            for (int j = 0; j < 4; j++) {
                float v = acc[i][j4 * 4 + j] + bb[j];
                if constexpr (EPI == 1) v = fmaxf(v, 0.f);
                if constexpr (EPI == 2) v = fmaxf(fmaf(v, sc[j], sh[j]), 0.f);
                vals[j] = v;
            }
            *(float4*)(C + (size_t)r * LDC + cb) = make_float4(vals[0], vals[1], vals[2], vals[3]);
        }
    }
}

// ---------------- pad w1_2 (256x40) into 256x64 (zero-filled) ----------------
__global__ void pad_w_kernel(const float* __restrict__ w, float* __restrict__ wp) {
    int i = blockIdx.x * 256 + threadIdx.x;
    if (i >= 256 * 64) return;
    int r = i >> 6, c = i & 63;
    wp[i] = (c < 40) ? w[r * 40 + c] : 0.f;
}

// ---------------- tail: relu(agg + b1) @ w2 + b2 -> log_softmax ----------------
__global__ __launch_bounds__(256) void final_kernel(
    const float* __restrict__ aggp, const float* __restrict__ b1,
    const float* __restrict__ w2, const float* __restrict__ b2,
    float* __restrict__ out, int n) {
    __shared__ float sw[40 * 40];
    __shared__ float sb1[40], sb2[40];
    for (int i = threadIdx.x; i < 1600; i += 256) sw[i] = w2[i];
    if (threadIdx.x < 40) { sb1[threadIdx.x] = b1[threadIdx.x]; sb2[threadIdx.x] = b2[threadIdx.x]; }
    __syncthreads();
    int row = blockIdx.x * 256 + threadIdx.x;
    if (row >= n) return;
    const float* ar = aggp + (size_t)row * 40;
    float t[40];
#pragma unroll
    for (int k = 0; k < 40; k++) t[k] = fmaxf(ar[k] + sb1[k], 0.f);
    float y[40];
#pragma unroll
    for (int j = 0; j < 40; j++) y[j] = sb2[j];
    for (int k = 0; k < 40; k++) {
        float tk = t[k];
#pragma unroll
        for (int j = 0; j < 40; j++) y[j] = fmaf(tk, sw[k * 40 + j], y[j]);
    }
    float m = -1e30f;
#pragma unroll
    for (int j = 0; j < 40; j++) m = fmaxf(m, y[j]);
    float s = 0.f;
#pragma unroll
    for (int j = 0; j < 40; j++) s += expf(y[j] - m);
    float lse = m + logf(s);
    float* orow = out + (size_t)row * 40;
#pragma unroll
    for (int j = 0; j < 40; j++) orow[j] = y[j] - lse;
}

extern "C" void kernel_launch(void* const* d_in, const int* in_sizes, int n_in,
                              void* d_out, int out_size, void* d_ws, size_t ws_size,
                              hipStream_t stream) {
    const float* x    = (const float*)d_in[0];
    const int*   ei   = (const int*)d_in[1];     // int64 in reference -> int32 on device
    const float* ew   = (const float*)d_in[2];
    const float* w1_0 = (const float*)d_in[3],  *b1_0 = (const float*)d_in[4];
    const float* w2_0 = (const float*)d_in[5],  *b2_0 = (const float*)d_in[6];
    const float* w1_1 = (const float*)d_in[7],  *b1_1 = (const float*)d_in[8];
    const float* w2_1 = (const float*)d_in[9],  *b2_1 = (const float*)d_in[10];
    const float* w1_2 = (const float*)d_in[11], *b1_2 = (const float*)d_in[12];
    const float* w2_2 = (const float*)d_in[13], *b2_2 = (const float*)d_in[14];
    const float* bng0 = (const float*)d_in[15], *bnb0 = (const float*)d_in[16];
    const float* bnm0 = (const float*)d_in[17], *bnv0 = (const float*)d_in[18];
    const float* bng1 = (const float*)d_in[19], *bnb1 = (const float*)d_in[20];
    const float* bnm1 = (const float*)d_in[21], *bnv1 = (const float*)d_in[22];
    float* out = (float*)d_out;

    char* wsp = (char*)d_ws;
    size_t off = 0;
    auto alloc = [&](size_t bytes) -> char* {
        char* p = wsp + off;
        off += (bytes + 255) & ~(size_t)255;
        return p;
    };
    int*   cursor  = (int*)alloc((size_t)NN * sizeof(int));
    int*   row_ptr = (int*)alloc((size_t)(NN + 1) * sizeof(int));
    int*   csr_src = (int*)alloc((size_t)NE * sizeof(int));
    float* csr_w   = (float*)alloc((size_t)NE * sizeof(float));
    float* bufA    = (float*)alloc((size_t)NN * 256 * sizeof(float));
    float* bufB    = (float*)alloc((size_t)NN * 256 * sizeof(float));
    float* wpad    = (float*)alloc(256 * 64 * sizeof(float));

    // CSR build (per call; edge order from atomics varies only fp summation order)
    hipMemsetAsync(cursor, 0, (size_t)NN * sizeof(int), stream);
    count_deg_kernel<<<(NE + 255) / 256, 256, 0, stream>>>(ei, cursor, NE);
    scan_kernel<<<1, 1024, 0, stream>>>(cursor, row_ptr, NN);
    fill_csr_kernel<<<(NE + 255) / 256, 256, 0, stream>>>(ei, ew, cursor, csr_src, csr_w, NE);
    pad_w_kernel<<<64, 256, 0, stream>>>(w1_2, wpad);

    dim3 gBig((NN + 127) / 128, 2);
    dim3 gSm((NN + 127) / 128, 1);
    int aggBlocks = (NN + 3) / 4;

    // ---- layer 0: agg -> relu(.@w1+b1) -> bn(relu(.@w2+b2)) relu ----
    aggregate_kernel<128><<<aggBlocks, 256, 0, stream>>>(x, row_ptr, csr_src, csr_w, bufA, NN);
    gemm_kernel<128, 128, 16, 8, 8, 1><<<gBig, 256, 0, stream>>>(
        bufA, w1_0, bufB, NN, 128, 256, 256, 256, b1_0, nullptr, nullptr, nullptr, nullptr);
    gemm_kernel<128, 128, 16, 8, 8, 2><<<gBig, 256, 0, stream>>>(
        bufB, w2_0, bufA, NN, 256, 256, 256, 256, b2_0, bng0, bnb0, bnm0, bnv0);

    // ---- layer 1 ----
    aggregate_kernel<256><<<aggBlocks, 256, 0, stream>>>(bufA, row_ptr, csr_src, csr_w, bufB, NN);
    gemm_kernel<128, 128, 16, 8, 8, 1><<<gBig, 256, 0, stream>>>(
        bufB, w1_1, bufA, NN, 256, 256, 256, 256, b1_1, nullptr, nullptr, nullptr, nullptr);
    gemm_kernel<128, 128, 16, 8, 8, 2><<<gBig, 256, 0, stream>>>(
        bufA, w2_1, bufB, NN, 256, 256, 256, 256, b2_1, bng1, bnb1, bnm1, bnv1);

    // ---- layer 2 (reordered: p = h2 @ w1_2 first, then scatter on 40 channels) ----
    gemm_kernel<128, 64, 16, 8, 4, 0><<<gSm, 256, 0, stream>>>(
        bufB, wpad, bufA, NN, 256, 64, 40, 40, nullptr, nullptr, nullptr, nullptr, nullptr);
    aggregate_kernel<40><<<aggBlocks, 256, 0, stream>>>(bufA, row_ptr, csr_src, csr_w, bufB, NN);
    final_kernel<<<(NN + 255) / 256, 256, 0, stream>>>(bufB, b1_2, w2_2, b2_2, out, NN);
}

// Round 3
// 640.702 us; speedup vs baseline: 1.4170x; 1.4170x over previous
//
#include <hip/hip_runtime.h>
#include <cstdint>
#include <cstddef>

#define BN_EPS 1e-5f

typedef unsigned short u16;
typedef __attribute__((ext_vector_type(8))) short bf16x8;   // 8 bf16 (4 VGPRs)
typedef __attribute__((ext_vector_type(4))) float f32x4;

constexpr int NN = 50000;
constexpr int NE = 800000;

__device__ __forceinline__ u16 f2bf(float f) {
    unsigned u = __float_as_uint(f);
    return (u16)((u + 0x7fffu + ((u >> 16) & 1u)) >> 16);   // RNE
}
__device__ __forceinline__ float bf2f(u16 h) { return __uint_as_float(((unsigned)h) << 16); }

// ---------------- CSR build (edge_index arrives as int32) ----------------
__global__ void count_deg_kernel(const int* __restrict__ ei, int* __restrict__ deg, int E) {
    int e = blockIdx.x * blockDim.x + threadIdx.x;
    if (e >= E) return;
    int d = ei[E + e];
    if ((unsigned)d < (unsigned)NN) atomicAdd(&deg[d], 1);
}

__global__ __launch_bounds__(256) void block_reduce_kernel(const int* __restrict__ deg,
                                                           int* __restrict__ blockSum, int n) {
    __shared__ int red[256];
    int i = blockIdx.x * 256 + threadIdx.x;
    red[threadIdx.x] = (i < n) ? deg[i] : 0;
    __syncthreads();
    for (int s = 128; s > 0; s >>= 1) {
        if (threadIdx.x < s) red[threadIdx.x] += red[threadIdx.x + s];
        __syncthreads();
    }
    if (threadIdx.x == 0) blockSum[blockIdx.x] = red[0];
}

__global__ __launch_bounds__(256) void scan_blocksums_kernel(const int* __restrict__ blockSum,
                                                             int* __restrict__ blockOff, int nb,
                                                             int* __restrict__ rowptr_last) {
    __shared__ int lds[256];
    int t = threadIdx.x;
    int v = (t < nb) ? blockSum[t] : 0;
    lds[t] = v;
    __syncthreads();
    for (int off = 1; off < 256; off <<= 1) {
        int u = (t >= off) ? lds[t - off] : 0;
        __syncthreads();
        lds[t] += u;
        __syncthreads();
    }
    if (t < nb) blockOff[t] = lds[t] - v;  // exclusive
    if (t == 255) *rowptr_last = lds[255];
}

// deg and cursor may alias (each thread touches only index i; reads precede writes)
__global__ __launch_bounds__(256) void block_scan_kernel(const int* deg,
                                                         const int* __restrict__ blockOff,
                                                         int* __restrict__ row_ptr,
                                                         int* cursor, int n) {
    __shared__ int lds[256];
    int t = threadIdx.x;
    int i = blockIdx.x * 256 + t;
    int v = (i < n) ? deg[i] : 0;
    lds[t] = v;
    __syncthreads();
    for (int off = 1; off < 256; off <<= 1) {
        int u = (t >= off) ? lds[t - off] : 0;
        __syncthreads();
        lds[t] += u;
        __syncthreads();
    }
    if (i < n) {
        int ex = blockOff[blockIdx.x] + lds[t] - v;
        row_ptr[i] = ex;
        cursor[i] = ex;
    }
}

__global__ void fill_csr_kernel(const int* __restrict__ ei, const float* __restrict__ ew,
                                int* __restrict__ cursor, int* __restrict__ csr_src,
                                float* __restrict__ csr_w, int E) {
    int e = blockIdx.x * blockDim.x + threadIdx.x;
    if (e >= E) return;
    int d = ei[E + e];
    int s = ei[e];
    if ((unsigned)d >= (unsigned)NN || (unsigned)s >= (unsigned)NN) return;
    int pos = atomicAdd(&cursor[d], 1);
    if (pos < E) { csr_src[pos] = s; csr_w[pos] = ew[e]; }
}

// ---------------- weight prep: transpose + hi/lo bf16 split ----------------
__global__ void wsplit_kernel(const float* __restrict__ w, u16* __restrict__ hiT,
                              u16* __restrict__ loT, int din, int dout) {
    int i = blockIdx.x * 256 + threadIdx.x;
    if (i >= din * dout) return;
    int k = i / dout, n = i - k * dout;
    float v = w[i];
    u16 h = f2bf(v);
    hiT[(size_t)n * din + k] = h;
    loT[(size_t)n * din + k] = f2bf(v - bf2f(h));
}

// w1_2 (256x40) -> padded transposed [64][256]
__global__ void wsplit_pad_kernel(const float* __restrict__ w, u16* __restrict__ hiT,
                                  u16* __restrict__ loT) {
    int i = blockIdx.x * 256 + threadIdx.x;
    if (i >= 64 * 256) return;
    int n = i >> 8, k = i & 255;
    float v = (n < 40) ? w[k * 40 + n] : 0.f;
    u16 h = f2bf(v);
    hiT[i] = h;
    loT[i] = f2bf(v - bf2f(h));
}

// ---------------- pull aggregation: out[n] = x[n] + sum_e w_e * x[src_e] ----------------
// INHL: input is (hi,lo) bf16 pair; OUTHL: output written as (hi,lo) bf16 pair
template <int C, int INHL, int OUTHL>
__global__ __launch_bounds__(256) void aggregate_kernel(
    const float* __restrict__ xf, const u16* __restrict__ xhi, const u16* __restrict__ xlo,
    const int* __restrict__ row_ptr, const int* __restrict__ csr_src,
    const float* __restrict__ csr_w,
    float* __restrict__ outf, u16* __restrict__ outhi, u16* __restrict__ outlo, int n) {
    int node = blockIdx.x * 4 + (threadIdx.x >> 6);
    if (node >= n) return;
    int lane = threadIdx.x & 63;
    constexpr int V = (C == 128) ? 2 : 4;
    if (C == 40 && lane >= 10) return;
    int col = lane * V;
    int beg = row_ptr[node], end = row_ptr[node + 1];

    auto loadv = [&](size_t idx, float* dst) {
        if constexpr (INHL) {
            if constexpr (V == 2) {
                ushort2 h = *(const ushort2*)(xhi + idx);
                ushort2 l = *(const ushort2*)(xlo + idx);
                dst[0] = bf2f(h.x) + bf2f(l.x);
                dst[1] = bf2f(h.y) + bf2f(l.y);
            } else {
                ushort4 h = *(const ushort4*)(xhi + idx);
                ushort4 l = *(const ushort4*)(xlo + idx);
                dst[0] = bf2f(h.x) + bf2f(l.x);
                dst[1] = bf2f(h.y) + bf2f(l.y);
                dst[2] = bf2f(h.z) + bf2f(l.z);
                dst[3] = bf2f(h.w) + bf2f(l.w);
            }
        } else {
            if constexpr (V == 2) {
                float2 v = *(const float2*)(xf + idx);
                dst[0] = v.x; dst[1] = v.y;
            } else {
                float4 v = *(const float4*)(xf + idx);
                dst[0] = v.x; dst[1] = v.y; dst[2] = v.z; dst[3] = v.w;
            }
        }
    };

    float acc[V];
    loadv((size_t)node * C + col, acc);  // self term (eps=0)
    for (int e = beg; e < end; ++e) {
        int s = csr_src[e];
        float w = csr_w[e];
        float t[V];
        loadv((size_t)s * C + col, t);
#pragma unroll
        for (int v = 0; v < V; v++) acc[v] = fmaf(w, t[v], acc[v]);
    }

    size_t ob = (size_t)node * C + col;
    if constexpr (OUTHL) {
        if constexpr (V == 2) {
            ushort2 h, l;
            h.x = f2bf(acc[0]); l.x = f2bf(acc[0] - bf2f(h.x));
            h.y = f2bf(acc[1]); l.y = f2bf(acc[1] - bf2f(h.y));
            *(ushort2*)(outhi + ob) = h;
            *(ushort2*)(outlo + ob) = l;
        } else {
            ushort4 h, l;
            h.x = f2bf(acc[0]); l.x = f2bf(acc[0] - bf2f(h.x));
            h.y = f2bf(acc[1]); l.y = f2bf(acc[1] - bf2f(h.y));
            h.z = f2bf(acc[2]); l.z = f2bf(acc[2] - bf2f(h.z));
            h.w = f2bf(acc[3]); l.w = f2bf(acc[3] - bf2f(h.w));
            *(ushort4*)(outhi + ob) = h;
            *(ushort4*)(outlo + ob) = l;
        }
    } else {
        if constexpr (V == 2) {
            *(float2*)(outf + ob) = make_float2(acc[0], acc[1]);
        } else {
            *(float4*)(outf + ob) = make_float4(acc[0], acc[1], acc[2], acc[3]);
        }
    }
}

// ---------------- split-bf16 MFMA GEMM: out = epilogue(A @ B) ----------------
// A: (hi,lo) bf16 row-major M x K.  B: (hi,lo) bf16 TRANSPOSED [N][K].
// BM=128, BK=32 fixed. EPI: 0 none, 1 bias+relu, 2 bias+BN+relu.
// OUTHL: 1 -> write (hi,lo) bf16 pair, 0 -> write fp32.
template <int BN, int EPI, int OUTHL>
__global__ __launch_bounds__(256) void gemm_mfma_kernel(
    const u16* __restrict__ Ahi, const u16* __restrict__ Alo,
    const u16* __restrict__ Bhi, const u16* __restrict__ Blo,
    float* __restrict__ outf, u16* __restrict__ outhi, u16* __restrict__ outlo,
    int M, int K, int LDC, int NSTORE,
    const float* __restrict__ bias,
    const float* __restrict__ bng, const float* __restrict__ bnb,
    const float* __restrict__ bnm, const float* __restrict__ bnv) {
    constexpr int WGN = (BN == 128) ? 2 : 1;
    constexpr int WGM = 4 / WGN;
    constexpr int WTM = 128 / WGM;  // wave tile M: 64 or 32
    constexpr int MF = WTM / 16;    // m-fragments per wave: 4 or 2
    constexpr int NF = 4;           // 64/16
    __shared__ u16 Al[2][128][40];  // [hi/lo][row][k] stride 40 (80B, 16B-aligned)
    __shared__ u16 Bl[2][BN][40];

    const int tid = threadIdx.x;
    const int lane = tid & 63;
    const int wid = tid >> 6;
    const int wm = wid / WGN, wn = wid % WGN;
    const int m0 = blockIdx.x * 128, n0 = blockIdx.y * BN;
    const int ln = lane & 15, l4 = lane >> 4;

    f32x4 acc[MF][NF];
#pragma unroll
    for (int mi = 0; mi < MF; mi++)
#pragma unroll
        for (int ni = 0; ni < NF; ni++) acc[mi][ni] = (f32x4){0.f, 0.f, 0.f, 0.f};

    for (int k0 = 0; k0 < K; k0 += 32) {
        // stage A tile (both hi and lo): 128 rows x 32 k = 4 x 16B chunks/row
#pragma unroll
        for (int rep = 0; rep < 4; rep++) {
            int idx = rep * 256 + tid;          // 0..1023
            int arr = idx >> 9;                 // 0=hi,1=lo
            int rc = idx & 511;
            int row = rc >> 2, c16 = rc & 3;
            const u16* src = arr ? Alo : Ahi;
            int gm = m0 + row;
            if (gm > M - 1) gm = M - 1;
            uint4 v = *(const uint4*)(src + (size_t)gm * K + k0 + c16 * 8);
            *(uint4*)(&Al[arr][row][c16 * 8]) = v;
        }
        // stage B tile
#pragma unroll
        for (int rep = 0; rep < BN / 32; rep++) {
            int idx = rep * 256 + tid;
            int arr = idx / (BN * 4);
            int rc = idx % (BN * 4);
            int row = rc >> 2, c16 = rc & 3;
            const u16* src = arr ? Blo : Bhi;
            uint4 v = *(const uint4*)(src + (size_t)(n0 + row) * K + k0 + c16 * 8);
            *(uint4*)(&Bl[arr][row][c16 * 8]) = v;
        }
        __syncthreads();

        bf16x8 ah[MF], al[MF], bh[NF], bl[NF];
#pragma unroll
        for (int mi = 0; mi < MF; mi++) {
            ah[mi] = *(const bf16x8*)(&Al[0][wm * WTM + mi * 16 + ln][l4 * 8]);
            al[mi] = *(const bf16x8*)(&Al[1][wm * WTM + mi * 16 + ln][l4 * 8]);
        }
#pragma unroll
        for (int ni = 0; ni < NF; ni++) {
            bh[ni] = *(const bf16x8*)(&Bl[0][wn * 64 + ni * 16 + ln][l4 * 8]);
            bl[ni] = *(const bf16x8*)(&Bl[1][wn * 64 + ni * 16 + ln][l4 * 8]);
        }
#pragma unroll
        for (int mi = 0; mi < MF; mi++)
#pragma unroll
            for (int ni = 0; ni < NF; ni++) {
                acc[mi][ni] = __builtin_amdgcn_mfma_f32_16x16x32_bf16(ah[mi], bh[ni], acc[mi][ni], 0, 0, 0);
                acc[mi][ni] = __builtin_amdgcn_mfma_f32_16x16x32_bf16(ah[mi], bl[ni], acc[mi][ni], 0, 0, 0);
                acc[mi][ni] = __builtin_amdgcn_mfma_f32_16x16x32_bf16(al[mi], bh[ni], acc[mi][ni], 0, 0, 0);
            }
        __syncthreads();
    }

    // epilogue: C/D layout col=lane&15, row=(lane>>4)*4+reg
#pragma unroll
    for (int ni = 0; ni < NF; ni++) {
        int c = n0 + wn * 64 + ni * 16 + ln;
        float bb = 0.f, sc = 1.f, sh = 0.f;
        if constexpr (EPI >= 1) bb = bias[c];
        if constexpr (EPI == 2) {
            float s = bng[c] * rsqrtf(bnv[c] + BN_EPS);
            sc = s;
            sh = bnb[c] - bnm[c] * s;
        }
        bool cok = (c < NSTORE);
#pragma unroll
        for (int mi = 0; mi < MF; mi++) {
#pragma unroll
            for (int r = 0; r < 4; r++) {
                int row = m0 + wm * WTM + mi * 16 + l4 * 4 + r;
                if (row < M && cok) {
                    float v = acc[mi][ni][r] + bb;
                    if constexpr (EPI == 1) v = fmaxf(v, 0.f);
                    if constexpr (EPI == 2) v = fmaxf(fmaf(v, sc, sh), 0.f);
                    size_t o = (size_t)row * LDC + c;
                    if constexpr (OUTHL) {
                        u16 h = f2bf(v);
                        outhi[o] = h;
                        outlo[o] = f2bf(v - bf2f(h));
                    } else {
                        outf[o] = v;
                    }
                }
            }
        }
    }
}

// ---------------- tail: relu(agg + b1) @ w2 + b2 -> log_softmax ----------------
__global__ __launch_bounds__(256) void final_kernel(
    const float* __restrict__ aggp, const float* __restrict__ b1,
    const float* __restrict__ w2, const float* __restrict__ b2,
    float* __restrict__ out, int n) {
    __shared__ float sw[40 * 40];
    __shared__ float sb1[40], sb2[40];
    for (int i = threadIdx.x; i < 1600; i += 256) sw[i] = w2[i];
    if (threadIdx.x < 40) { sb1[threadIdx.x] = b1[threadIdx.x]; sb2[threadIdx.x] = b2[threadIdx.x]; }
    __syncthreads();
    int row = blockIdx.x * 256 + threadIdx.x;
    if (row >= n) return;
    const float* ar = aggp + (size_t)row * 40;
    float t[40];
#pragma unroll
    for (int k = 0; k < 40; k++) t[k] = fmaxf(ar[k] + sb1[k], 0.f);
    float y[40];
#pragma unroll
    for (int j = 0; j < 40; j++) y[j] = sb2[j];
    for (int k = 0; k < 40; k++) {
        float tk = t[k];
#pragma unroll
        for (int j = 0; j < 40; j++) y[j] = fmaf(tk, sw[k * 40 + j], y[j]);
    }
    float m = -1e30f;
#pragma unroll
    for (int j = 0; j < 40; j++) m = fmaxf(m, y[j]);
    float s = 0.f;
#pragma unroll
    for (int j = 0; j < 40; j++) s += expf(y[j] - m);
    float lse = m + logf(s);
    float* orow = out + (size_t)row * 40;
#pragma unroll
    for (int j = 0; j < 40; j++) orow[j] = y[j] - lse;
}

extern "C" void kernel_launch(void* const* d_in, const int* in_sizes, int n_in,
                              void* d_out, int out_size, void* d_ws, size_t ws_size,
                              hipStream_t stream) {
    const float* x    = (const float*)d_in[0];
    const int*   ei   = (const int*)d_in[1];  // int64 in ref -> int32 on device
    const float* ew   = (const float*)d_in[2];
    const float* w1_0 = (const float*)d_in[3],  *b1_0 = (const float*)d_in[4];
    const float* w2_0 = (const float*)d_in[5],  *b2_0 = (const float*)d_in[6];
    const float* w1_1 = (const float*)d_in[7],  *b1_1 = (const float*)d_in[8];
    const float* w2_1 = (const float*)d_in[9],  *b2_1 = (const float*)d_in[10];
    const float* w1_2 = (const float*)d_in[11], *b1_2 = (const float*)d_in[12];
    const float* w2_2 = (const float*)d_in[13], *b2_2 = (const float*)d_in[14];
    const float* bng0 = (const float*)d_in[15], *bnb0 = (const float*)d_in[16];
    const float* bnm0 = (const float*)d_in[17], *bnv0 = (const float*)d_in[18];
    const float* bng1 = (const float*)d_in[19], *bnb1 = (const float*)d_in[20];
    const float* bnm1 = (const float*)d_in[21], *bnv1 = (const float*)d_in[22];
    float* out = (float*)d_out;

    char* wsp = (char*)d_ws;
    size_t off = 0;
    auto alloc = [&](size_t bytes) -> char* {
        char* p = wsp + off;
        off += (bytes + 255) & ~(size_t)255;
        return p;
    };
    int*   cursor   = (int*)alloc((size_t)NN * sizeof(int));
    int*   row_ptr  = (int*)alloc((size_t)(NN + 1) * sizeof(int));
    int*   blockSum = (int*)alloc(256 * sizeof(int));
    int*   blockOff = (int*)alloc(256 * sizeof(int));
    int*   csr_src  = (int*)alloc((size_t)NE * sizeof(int));
    float* csr_w    = (float*)alloc((size_t)NE * sizeof(float));
    u16* A = (u16*)alloc((size_t)NN * 256 * sizeof(u16));
    u16* B = (u16*)alloc((size_t)NN * 256 * sizeof(u16));
    u16* C = (u16*)alloc((size_t)NN * 256 * sizeof(u16));
    u16* D = (u16*)alloc((size_t)NN * 256 * sizeof(u16));
    u16* w10h = (u16*)alloc(128 * 256 * 2); u16* w10l = (u16*)alloc(128 * 256 * 2);
    u16* w20h = (u16*)alloc(256 * 256 * 2); u16* w20l = (u16*)alloc(256 * 256 * 2);
    u16* w11h = (u16*)alloc(256 * 256 * 2); u16* w11l = (u16*)alloc(256 * 256 * 2);
    u16* w21h = (u16*)alloc(256 * 256 * 2); u16* w21l = (u16*)alloc(256 * 256 * 2);
    u16* wph  = (u16*)alloc(64 * 256 * 2);  u16* wpl  = (u16*)alloc(64 * 256 * 2);

    const int NB = (NN + 255) / 256;  // 196

    // --- CSR build (parallel scan) ---
    hipMemsetAsync(cursor, 0, (size_t)NN * sizeof(int), stream);
    count_deg_kernel<<<(NE + 255) / 256, 256, 0, stream>>>(ei, cursor, NE);
    block_reduce_kernel<<<NB, 256, 0, stream>>>(cursor, blockSum, NN);
    scan_blocksums_kernel<<<1, 256, 0, stream>>>(blockSum, blockOff, NB, row_ptr + NN);
    block_scan_kernel<<<NB, 256, 0, stream>>>(cursor, blockOff, row_ptr, cursor, NN);
    fill_csr_kernel<<<(NE + 255) / 256, 256, 0, stream>>>(ei, ew, cursor, csr_src, csr_w, NE);

    // --- weight prep ---
    wsplit_kernel<<<(128 * 256 + 255) / 256, 256, 0, stream>>>(w1_0, w10h, w10l, 128, 256);
    wsplit_kernel<<<(256 * 256 + 255) / 256, 256, 0, stream>>>(w2_0, w20h, w20l, 256, 256);
    wsplit_kernel<<<(256 * 256 + 255) / 256, 256, 0, stream>>>(w1_1, w11h, w11l, 256, 256);
    wsplit_kernel<<<(256 * 256 + 255) / 256, 256, 0, stream>>>(w2_1, w21h, w21l, 256, 256);
    wsplit_pad_kernel<<<64, 256, 0, stream>>>(w1_2, wph, wpl);

    const int aggBlocks = (NN + 3) / 4;
    dim3 gBig((NN + 127) / 128, 2);
    dim3 gSm((NN + 127) / 128, 1);

    // ---- layer 0 ----
    aggregate_kernel<128, 0, 1><<<aggBlocks, 256, 0, stream>>>(
        x, nullptr, nullptr, row_ptr, csr_src, csr_w, nullptr, A, B, NN);
    gemm_mfma_kernel<128, 1, 1><<<gBig, 256, 0, stream>>>(
        A, B, w10h, w10l, nullptr, C, D, NN, 128, 256, 256,
        b1_0, nullptr, nullptr, nullptr, nullptr);
    gemm_mfma_kernel<128, 2, 1><<<gBig, 256, 0, stream>>>(
        C, D, w20h, w20l, nullptr, A, B, NN, 256, 256, 256,
        b2_0, bng0, bnb0, bnm0, bnv0);

    // ---- layer 1 ----
    aggregate_kernel<256, 1, 1><<<aggBlocks, 256, 0, stream>>>(
        nullptr, A, B, row_ptr, csr_src, csr_w, nullptr, C, D, NN);
    gemm_mfma_kernel<128, 1, 1><<<gBig, 256, 0, stream>>>(
        C, D, w11h, w11l, nullptr, A, B, NN, 256, 256, 256,
        b1_1, nullptr, nullptr, nullptr, nullptr);
    gemm_mfma_kernel<128, 2, 1><<<gBig, 256, 0, stream>>>(
        A, B, w21h, w21l, nullptr, C, D, NN, 256, 256, 256,
        b2_1, bng1, bnb1, bnm1, bnv1);

    // ---- layer 2 (reordered: p = h @ w1_2 first, then aggregate 40 channels) ----
    float* p    = (float*)A;  // 8 MB < 25.6 MB region
    float* aggp = (float*)B;
    gemm_mfma_kernel<64, 0, 0><<<gSm, 256, 0, stream>>>(
        C, D, wph, wpl, p, nullptr, nullptr, NN, 256, 40, 40,
        nullptr, nullptr, nullptr, nullptr, nullptr);
    aggregate_kernel<40, 0, 0><<<aggBlocks, 256, 0, stream>>>(
        p, nullptr, nullptr, row_ptr, csr_src, csr_w, aggp, nullptr, nullptr, NN);
    final_kernel<<<NB, 256, 0, stream>>>(aggp, b1_2, w2_2, b2_2, out, NN);
}

// Round 5
// 630.858 us; speedup vs baseline: 1.4391x; 1.0156x over previous
//
#include <hip/hip_runtime.h>
#include <cstdint>
#include <cstddef>

#define BN_EPS 1e-5f

typedef unsigned short u16;
typedef __attribute__((ext_vector_type(8))) short bf16x8;   // 8 bf16 (4 VGPRs)
typedef __attribute__((ext_vector_type(4))) float f32x4;

constexpr int NN = 50000;
constexpr int NE = 800000;

__device__ __forceinline__ u16 f2bf(float f) {
    unsigned u = __float_as_uint(f);
    return (u16)((u + 0x7fffu + ((u >> 16) & 1u)) >> 16);   // RNE
}
__device__ __forceinline__ float bf2f(u16 h) { return __uint_as_float(((unsigned)h) << 16); }

// ---------------- CSR build (edge_index arrives as int32) ----------------
__global__ void count_deg_kernel(const int* __restrict__ ei, int* __restrict__ deg, int E) {
    int e = blockIdx.x * blockDim.x + threadIdx.x;
    if (e >= E) return;
    int d = ei[E + e];
    if ((unsigned)d < (unsigned)NN) atomicAdd(&deg[d], 1);
}

__global__ __launch_bounds__(256) void block_reduce_kernel(const int* __restrict__ deg,
                                                           int* __restrict__ blockSum, int n) {
    __shared__ int red[256];
    int i = blockIdx.x * 256 + threadIdx.x;
    red[threadIdx.x] = (i < n) ? deg[i] : 0;
    __syncthreads();
    for (int s = 128; s > 0; s >>= 1) {
        if (threadIdx.x < s) red[threadIdx.x] += red[threadIdx.x + s];
        __syncthreads();
    }
    if (threadIdx.x == 0) blockSum[blockIdx.x] = red[0];
}

__global__ __launch_bounds__(256) void scan_blocksums_kernel(const int* __restrict__ blockSum,
                                                             int* __restrict__ blockOff, int nb,
                                                             int* __restrict__ rowptr_last) {
    __shared__ int lds[256];
    int t = threadIdx.x;
    int v = (t < nb) ? blockSum[t] : 0;
    lds[t] = v;
    __syncthreads();
    for (int off = 1; off < 256; off <<= 1) {
        int u = (t >= off) ? lds[t - off] : 0;
        __syncthreads();
        lds[t] += u;
        __syncthreads();
    }
    if (t < nb) blockOff[t] = lds[t] - v;  // exclusive
    if (t == 255) *rowptr_last = lds[255];
}

// deg and cursor may alias (each thread touches only index i; reads precede writes)
__global__ __launch_bounds__(256) void block_scan_kernel(const int* deg,
                                                         const int* __restrict__ blockOff,
                                                         int* __restrict__ row_ptr,
                                                         int* cursor, int n) {
    __shared__ int lds[256];
    int t = threadIdx.x;
    int i = blockIdx.x * 256 + t;
    int v = (i < n) ? deg[i] : 0;
    lds[t] = v;
    __syncthreads();
    for (int off = 1; off < 256; off <<= 1) {
        int u = (t >= off) ? lds[t - off] : 0;
        __syncthreads();
        lds[t] += u;
        __syncthreads();
    }
    if (i < n) {
        int ex = blockOff[blockIdx.x] + lds[t] - v;
        row_ptr[i] = ex;
        cursor[i] = ex;
    }
}

__global__ void fill_csr_kernel(const int* __restrict__ ei, const float* __restrict__ ew,
                                int* __restrict__ cursor, int* __restrict__ csr_src,
                                float* __restrict__ csr_w, int E) {
    int e = blockIdx.x * blockDim.x + threadIdx.x;
    if (e >= E) return;
    int d = ei[E + e];
    int s = ei[e];
    if ((unsigned)d >= (unsigned)NN || (unsigned)s >= (unsigned)NN) return;
    int pos = atomicAdd(&cursor[d], 1);
    if (pos < E) { csr_src[pos] = s; csr_w[pos] = ew[e]; }
}

// ---------------- weight prep: transpose + hi/lo bf16 split ----------------
__global__ void wsplit_kernel(const float* __restrict__ w, u16* __restrict__ hiT,
                              u16* __restrict__ loT, int din, int dout) {
    int i = blockIdx.x * 256 + threadIdx.x;
    if (i >= din * dout) return;
    int k = i / dout, n = i - k * dout;
    float v = w[i];
    u16 h = f2bf(v);
    hiT[(size_t)n * din + k] = h;
    loT[(size_t)n * din + k] = f2bf(v - bf2f(h));
}

// w1_2 (256x40) -> padded transposed [64][256]
__global__ void wsplit_pad_kernel(const float* __restrict__ w, u16* __restrict__ hiT,
                                  u16* __restrict__ loT) {
    int i = blockIdx.x * 256 + threadIdx.x;
    if (i >= 64 * 256) return;
    int n = i >> 8, k = i & 255;
    float v = (n < 40) ? w[k * 40 + n] : 0.f;
    u16 h = f2bf(v);
    hiT[i] = h;
    loT[i] = f2bf(v - bf2f(h));
}

// ---------------- pull aggregation: out[n] = x[n] + sum_e w_e * x[src_e] ----------------
template <int C, int INHL, int OUTHL>
__global__ __launch_bounds__(256) void aggregate_kernel(
    const float* __restrict__ xf, const u16* __restrict__ xhi, const u16* __restrict__ xlo,
    const int* __restrict__ row_ptr, const int* __restrict__ csr_src,
    const float* __restrict__ csr_w,
    float* __restrict__ outf, u16* __restrict__ outhi, u16* __restrict__ outlo, int n) {
    int node = blockIdx.x * 4 + (threadIdx.x >> 6);
    if (node >= n) return;
    int lane = threadIdx.x & 63;
    constexpr int V = (C == 128) ? 2 : 4;
    if (C == 40 && lane >= 10) return;
    int col = lane * V;
    int beg = row_ptr[node], end = row_ptr[node + 1];

    auto loadv = [&](size_t idx, float* dst) {
        if constexpr (INHL) {
            if constexpr (V == 2) {
                ushort2 h = *(const ushort2*)(xhi + idx);
                ushort2 l = *(const ushort2*)(xlo + idx);
                dst[0] = bf2f(h.x) + bf2f(l.x);
                dst[1] = bf2f(h.y) + bf2f(l.y);
            } else {
                ushort4 h = *(const ushort4*)(xhi + idx);
                ushort4 l = *(const ushort4*)(xlo + idx);
                dst[0] = bf2f(h.x) + bf2f(l.x);
                dst[1] = bf2f(h.y) + bf2f(l.y);
                dst[2] = bf2f(h.z) + bf2f(l.z);
                dst[3] = bf2f(h.w) + bf2f(l.w);
            }
        } else {
            if constexpr (V == 2) {
                float2 v = *(const float2*)(xf + idx);
                dst[0] = v.x; dst[1] = v.y;
            } else {
                float4 v = *(const float4*)(xf + idx);
                dst[0] = v.x; dst[1] = v.y; dst[2] = v.z; dst[3] = v.w;
            }
        }
    };

    float acc[V];
    loadv((size_t)node * C + col, acc);  // self term (eps=0)
    for (int e = beg; e < end; ++e) {
        int s = csr_src[e];
        float w = csr_w[e];
        float t[V];
        loadv((size_t)s * C + col, t);
#pragma unroll
        for (int v = 0; v < V; v++) acc[v] = fmaf(w, t[v], acc[v]);
    }

    size_t ob = (size_t)node * C + col;
    if constexpr (OUTHL) {
        if constexpr (V == 2) {
            ushort2 h, l;
            h.x = f2bf(acc[0]); l.x = f2bf(acc[0] - bf2f(h.x));
            h.y = f2bf(acc[1]); l.y = f2bf(acc[1] - bf2f(h.y));
            *(ushort2*)(outhi + ob) = h;
            *(ushort2*)(outlo + ob) = l;
        } else {
            ushort4 h, l;
            h.x = f2bf(acc[0]); l.x = f2bf(acc[0] - bf2f(h.x));
            h.y = f2bf(acc[1]); l.y = f2bf(acc[1] - bf2f(h.y));
            h.z = f2bf(acc[2]); l.z = f2bf(acc[2] - bf2f(h.z));
            h.w = f2bf(acc[3]); l.w = f2bf(acc[3] - bf2f(h.w));
            *(ushort4*)(outhi + ob) = h;
            *(ushort4*)(outlo + ob) = l;
        }
    } else {
        if constexpr (V == 2) {
            *(float2*)(outf + ob) = make_float2(acc[0], acc[1]);
        } else {
            *(float4*)(outf + ob) = make_float4(acc[0], acc[1], acc[2], acc[3]);
        }
    }
}

// ---------------- split-bf16 MFMA GEMM v2: BK=64, XOR-swizzled linear LDS ----------------
// A: (hi,lo) bf16 row-major M x K.  B: (hi,lo) bf16 TRANSPOSED [N][K].
// BM=128. EPI: 0 none, 1 bias+relu, 2 bias+BN+relu. OUTHL: 1 -> (hi,lo) pair, 0 -> fp32.
// LDS rows: 64 u16 = 128 B = 8 x 16B chunks. Swizzle byte ^= (row&7)<<4 on BOTH sides.
template <int BN_, int EPI, int OUTHL>
__global__ __launch_bounds__(256, 2) void gemm_mfma_kernel(
    const u16* __restrict__ Ahi, const u16* __restrict__ Alo,
    const u16* __restrict__ Bhi, const u16* __restrict__ Blo,
    float* __restrict__ outf, u16* __restrict__ outhi, u16* __restrict__ outlo,
    int M, int K, int LDC, int NSTORE,
    const float* __restrict__ bias,
    const float* __restrict__ bng, const float* __restrict__ bnb,
    const float* __restrict__ bnm, const float* __restrict__ bnv) {
    constexpr int WGN = (BN_ == 128) ? 2 : 1;
    constexpr int WGM = 4 / WGN;
    constexpr int WTM = 128 / WGM;  // wave tile M: 64 or 32
    constexpr int MF = WTM / 16;    // 4 or 2
    constexpr int NF = 4;           // wave tile N = 64
    __shared__ __attribute__((aligned(16))) u16 Ahl[2][128][64];
    __shared__ __attribute__((aligned(16))) u16 Bhl[2][BN_][64];

    const int tid = threadIdx.x;
    const int lane = tid & 63;
    const int wid = tid >> 6;
    const int wm = wid / WGN, wn = wid % WGN;
    const int m0 = blockIdx.x * 128, n0 = blockIdx.y * BN_;
    const int ln = lane & 15, l4 = lane >> 4;

    f32x4 acc[MF][NF];
#pragma unroll
    for (int mi = 0; mi < MF; mi++)
#pragma unroll
        for (int ni = 0; ni < NF; ni++) acc[mi][ni] = (f32x4){0.f, 0.f, 0.f, 0.f};

    for (int k0 = 0; k0 < K; k0 += 64) {
        // stage A: [2 planes][128 rows][8 x 16B chunks] = 2048 chunks, 8 reps
#pragma unroll
        for (int rep = 0; rep < 8; rep++) {
            int idx = rep * 256 + tid;
            int plane = idx >> 10;
            int rc = idx & 1023;
            int row = rc >> 3, c16 = rc & 7;
            const u16* src = plane ? Alo : Ahi;
            int gm = m0 + row;
            if (gm > M - 1) gm = M - 1;
            uint4 v = *(const uint4*)(src + (size_t)gm * K + k0 + c16 * 8);
            int sb = (c16 * 16) ^ ((row & 7) << 4);
            *(uint4*)((char*)&Ahl[plane][row][0] + sb) = v;
        }
        // stage B: [2][BN_][8] = BN_*16 chunks, BN_/16 reps
#pragma unroll
        for (int rep = 0; rep < BN_ / 16; rep++) {
            int idx = rep * 256 + tid;
            int plane = idx / (BN_ * 8);
            int rc = idx % (BN_ * 8);
            int row = rc >> 3, c16 = rc & 7;
            const u16* src = plane ? Blo : Bhi;
            uint4 v = *(const uint4*)(src + (size_t)(n0 + row) * K + k0 + c16 * 8);
            int sb = (c16 * 16) ^ ((row & 7) << 4);
            *(uint4*)((char*)&Bhl[plane][row][0] + sb) = v;
        }
        __syncthreads();

#pragma unroll
        for (int kk = 0; kk < 2; kk++) {
            bf16x8 ah[MF], al[MF], bh[NF], bl[NF];
#pragma unroll
            for (int mi = 0; mi < MF; mi++) {
                int row = wm * WTM + mi * 16 + ln;
                int sb = (kk * 64 + l4 * 16) ^ ((row & 7) << 4);
                ah[mi] = *(const bf16x8*)((const char*)&Ahl[0][row][0] + sb);
                al[mi] = *(const bf16x8*)((const char*)&Ahl[1][row][0] + sb);
            }
#pragma unroll
            for (int ni = 0; ni < NF; ni++) {
                int row = wn * 64 + ni * 16 + ln;
                int sb = (kk * 64 + l4 * 16) ^ ((row & 7) << 4);
                bh[ni] = *(const bf16x8*)((const char*)&Bhl[0][row][0] + sb);
                bl[ni] = *(const bf16x8*)((const char*)&Bhl[1][row][0] + sb);
            }
#pragma unroll
            for (int mi = 0; mi < MF; mi++)
#pragma unroll
                for (int ni = 0; ni < NF; ni++) {
                    acc[mi][ni] = __builtin_amdgcn_mfma_f32_16x16x32_bf16(ah[mi], bh[ni], acc[mi][ni], 0, 0, 0);
                    acc[mi][ni] = __builtin_amdgcn_mfma_f32_16x16x32_bf16(ah[mi], bl[ni], acc[mi][ni], 0, 0, 0);
                    acc[mi][ni] = __builtin_amdgcn_mfma_f32_16x16x32_bf16(al[mi], bh[ni], acc[mi][ni], 0, 0, 0);
                }
        }
        __syncthreads();
    }

    // epilogue: C/D layout col=lane&15, row=(lane>>4)*4+reg
#pragma unroll
    for (int ni = 0; ni < NF; ni++) {
        int c = n0 + wn * 64 + ni * 16 + ln;
        float bb = 0.f, sc = 1.f, sh = 0.f;
        if constexpr (EPI >= 1) bb = bias[c];
        if constexpr (EPI == 2) {
            float s = bng[c] * rsqrtf(bnv[c] + BN_EPS);
            sc = s;
            sh = bnb[c] - bnm[c] * s;
        }
        bool cok = (c < NSTORE);
#pragma unroll
        for (int mi = 0; mi < MF; mi++) {
#pragma unroll
            for (int r = 0; r < 4; r++) {
                int row = m0 + wm * WTM + mi * 16 + l4 * 4 + r;
                if (row < M && cok) {
                    float v = acc[mi][ni][r] + bb;
                    if constexpr (EPI == 1) v = fmaxf(v, 0.f);
                    if constexpr (EPI == 2) v = fmaxf(fmaf(v, sc, sh), 0.f);
                    size_t o = (size_t)row * LDC + c;
                    if constexpr (OUTHL) {
                        u16 h = f2bf(v);
                        outhi[o] = h;
                        outlo[o] = f2bf(v - bf2f(h));
                    } else {
                        outf[o] = v;
                    }
                }
            }
        }
    }
}

// ---------------- tail: relu(agg + b1) @ w2 + b2 -> log_softmax ----------------
__global__ __launch_bounds__(256) void final_kernel(
    const float* __restrict__ aggp, const float* __restrict__ b1,
    const float* __restrict__ w2, const float* __restrict__ b2,
    float* __restrict__ out, int n) {
    __shared__ float sw[40 * 40];
    __shared__ float sb1[40], sb2[40];
    for (int i = threadIdx.x; i < 1600; i += 256) sw[i] = w2[i];
    if (threadIdx.x < 40) { sb1[threadIdx.x] = b1[threadIdx.x]; sb2[threadIdx.x] = b2[threadIdx.x]; }
    __syncthreads();
    int row = blockIdx.x * 256 + threadIdx.x;
    if (row >= n) return;
    const float* ar = aggp + (size_t)row * 40;
    float t[40];
#pragma unroll
    for (int k = 0; k < 40; k++) t[k] = fmaxf(ar[k] + sb1[k], 0.f);
    float y[40];
#pragma unroll
    for (int j = 0; j < 40; j++) y[j] = sb2[j];
    for (int k = 0; k < 40; k++) {
        float tk = t[k];
#pragma unroll
        for (int j = 0; j < 40; j++) y[j] = fmaf(tk, sw[k * 40 + j], y[j]);
    }
    float m = -1e30f;
#pragma unroll
    for (int j = 0; j < 40; j++) m = fmaxf(m, y[j]);
    float s = 0.f;
#pragma unroll
    for (int j = 0; j < 40; j++) s += expf(y[j] - m);
    float lse = m + logf(s);
    float* orow = out + (size_t)row * 40;
#pragma unroll
    for (int j = 0; j < 40; j++) orow[j] = y[j] - lse;
}

extern "C" void kernel_launch(void* const* d_in, const int* in_sizes, int n_in,
                              void* d_out, int out_size, void* d_ws, size_t ws_size,
                              hipStream_t stream) {
    const float* x    = (const float*)d_in[0];
    const int*   ei   = (const int*)d_in[1];  // int64 in ref -> int32 on device
    const float* ew   = (const float*)d_in[2];
    const float* w1_0 = (const float*)d_in[3],  *b1_0 = (const float*)d_in[4];
    const float* w2_0 = (const float*)d_in[5],  *b2_0 = (const float*)d_in[6];
    const float* w1_1 = (const float*)d_in[7],  *b1_1 = (const float*)d_in[8];
    const float* w2_1 = (const float*)d_in[9],  *b2_1 = (const float*)d_in[10];
    const float* w1_2 = (const float*)d_in[11], *b1_2 = (const float*)d_in[12];
    const float* w2_2 = (const float*)d_in[13], *b2_2 = (const float*)d_in[14];
    const float* bng0 = (const float*)d_in[15], *bnb0 = (const float*)d_in[16];
    const float* bnm0 = (const float*)d_in[17], *bnv0 = (const float*)d_in[18];
    const float* bng1 = (const float*)d_in[19], *bnb1 = (const float*)d_in[20];
    const float* bnm1 = (const float*)d_in[21], *bnv1 = (const float*)d_in[22];
    float* out = (float*)d_out;

    char* wsp = (char*)d_ws;
    size_t off = 0;
    auto alloc = [&](size_t bytes) -> char* {
        char* p = wsp + off;
        off += (bytes + 255) & ~(size_t)255;
        return p;
    };
    int*   cursor   = (int*)alloc((size_t)NN * sizeof(int));
    int*   row_ptr  = (int*)alloc((size_t)(NN + 1) * sizeof(int));
    int*   blockSum = (int*)alloc(256 * sizeof(int));
    int*   blockOff = (int*)alloc(256 * sizeof(int));
    int*   csr_src  = (int*)alloc((size_t)NE * sizeof(int));
    float* csr_w    = (float*)alloc((size_t)NE * sizeof(float));
    u16* A = (u16*)alloc((size_t)NN * 256 * sizeof(u16));
    u16* B = (u16*)alloc((size_t)NN * 256 * sizeof(u16));
    u16* C = (u16*)alloc((size_t)NN * 256 * sizeof(u16));
    u16* D = (u16*)alloc((size_t)NN * 256 * sizeof(u16));
    u16* w10h = (u16*)alloc(128 * 256 * 2); u16* w10l = (u16*)alloc(128 * 256 * 2);
    u16* w20h = (u16*)alloc(256 * 256 * 2); u16* w20l = (u16*)alloc(256 * 256 * 2);
    u16* w11h = (u16*)alloc(256 * 256 * 2); u16* w11l = (u16*)alloc(256 * 256 * 2);
    u16* w21h = (u16*)alloc(256 * 256 * 2); u16* w21l = (u16*)alloc(256 * 256 * 2);
    u16* wph  = (u16*)alloc(64 * 256 * 2);  u16* wpl  = (u16*)alloc(64 * 256 * 2);

    const int NB = (NN + 255) / 256;  // 196

    // --- CSR build (parallel scan) ---
    hipMemsetAsync(cursor, 0, (size_t)NN * sizeof(int), stream);
    count_deg_kernel<<<(NE + 255) / 256, 256, 0, stream>>>(ei, cursor, NE);
    block_reduce_kernel<<<NB, 256, 0, stream>>>(cursor, blockSum, NN);
    scan_blocksums_kernel<<<1, 256, 0, stream>>>(blockSum, blockOff, NB, row_ptr + NN);
    block_scan_kernel<<<NB, 256, 0, stream>>>(cursor, blockOff, row_ptr, cursor, NN);
    fill_csr_kernel<<<(NE + 255) / 256, 256, 0, stream>>>(ei, ew, cursor, csr_src, csr_w, NE);

    // --- weight prep ---
    wsplit_kernel<<<(128 * 256 + 255) / 256, 256, 0, stream>>>(w1_0, w10h, w10l, 128, 256);
    wsplit_kernel<<<(256 * 256 + 255) / 256, 256, 0, stream>>>(w2_0, w20h, w20l, 256, 256);
    wsplit_kernel<<<(256 * 256 + 255) / 256, 256, 0, stream>>>(w1_1, w11h, w11l, 256, 256);
    wsplit_kernel<<<(256 * 256 + 255) / 256, 256, 0, stream>>>(w2_1, w21h, w21l, 256, 256);
    wsplit_pad_kernel<<<64, 256, 0, stream>>>(w1_2, wph, wpl);

    const int aggBlocks = (NN + 3) / 4;
    dim3 gBig((NN + 127) / 128, 2);
    dim3 gSm((NN + 127) / 128, 1);

    // ---- layer 0 ----
    aggregate_kernel<128, 0, 1><<<aggBlocks, 256, 0, stream>>>(
        x, nullptr, nullptr, row_ptr, csr_src, csr_w, nullptr, A, B, NN);
    gemm_mfma_kernel<128, 1, 1><<<gBig, 256, 0, stream>>>(
        A, B, w10h, w10l, nullptr, C, D, NN, 128, 256, 256,
        b1_0, nullptr, nullptr, nullptr, nullptr);
    gemm_mfma_kernel<128, 2, 1><<<gBig, 256, 0, stream>>>(
        C, D, w20h, w20l, nullptr, A, B, NN, 256, 256, 256,
        b2_0, bng0, bnb0, bnm0, bnv0);

    // ---- layer 1 ----
    aggregate_kernel<256, 1, 1><<<aggBlocks, 256, 0, stream>>>(
        nullptr, A, B, row_ptr, csr_src, csr_w, nullptr, C, D, NN);
    gemm_mfma_kernel<128, 1, 1><<<gBig, 256, 0, stream>>>(
        C, D, w11h, w11l, nullptr, A, B, NN, 256, 256, 256,
        b1_1, nullptr, nullptr, nullptr, nullptr);
    gemm_mfma_kernel<128, 2, 1><<<gBig, 256, 0, stream>>>(
        A, B, w21h, w21l, nullptr, C, D, NN, 256, 256, 256,
        b2_1, bng1, bnb1, bnm1, bnv1);

    // ---- layer 2 (reordered: p = h @ w1_2 first, then aggregate 40 channels) ----
    float* p    = (float*)A;  // 8 MB < 25.6 MB region
    float* aggp = (float*)B;
    gemm_mfma_kernel<64, 0, 0><<<gSm, 256, 0, stream>>>(
        C, D, wph, wpl, p, nullptr, nullptr, NN, 256, 40, 40,
        nullptr, nullptr, nullptr, nullptr, nullptr);
    aggregate_kernel<40, 0, 0><<<aggBlocks, 256, 0, stream>>>(
        p, nullptr, nullptr, row_ptr, csr_src, csr_w, aggp, nullptr, nullptr, NN);
    final_kernel<<<NB, 256, 0, stream>>>(aggp, b1_2, w2_2, b2_2, out, NN);
}

// Round 6
// 555.288 us; speedup vs baseline: 1.6350x; 1.1361x over previous
//
#include <hip/hip_runtime.h>
#include <cstdint>
#include <cstddef>

#define BN_EPS 1e-5f

typedef unsigned short u16;
typedef __attribute__((ext_vector_type(8))) short bf16x8;   // 8 bf16 (4 VGPRs)
typedef __attribute__((ext_vector_type(4))) float f32x4;

constexpr int NN = 50000;
constexpr int NE = 800000;

__device__ __forceinline__ u16 f2bf(float f) {
    unsigned u = __float_as_uint(f);
    return (u16)((u + 0x7fffu + ((u >> 16) & 1u)) >> 16);   // RNE
}
__device__ __forceinline__ float bf2f(u16 h) { return __uint_as_float(((unsigned)h) << 16); }

// ---------------- CSR build (edge_index arrives as int32) ----------------
__global__ void count_deg_kernel(const int* __restrict__ ei, int* __restrict__ deg, int E) {
    int e = blockIdx.x * blockDim.x + threadIdx.x;
    if (e >= E) return;
    int d = ei[E + e];
    if ((unsigned)d < (unsigned)NN) atomicAdd(&deg[d], 1);
}

__global__ __launch_bounds__(256) void block_reduce_kernel(const int* __restrict__ deg,
                                                           int* __restrict__ blockSum, int n) {
    __shared__ int red[256];
    int i = blockIdx.x * 256 + threadIdx.x;
    red[threadIdx.x] = (i < n) ? deg[i] : 0;
    __syncthreads();
    for (int s = 128; s > 0; s >>= 1) {
        if (threadIdx.x < s) red[threadIdx.x] += red[threadIdx.x + s];
        __syncthreads();
    }
    if (threadIdx.x == 0) blockSum[blockIdx.x] = red[0];
}

__global__ __launch_bounds__(256) void scan_blocksums_kernel(const int* __restrict__ blockSum,
                                                             int* __restrict__ blockOff, int nb,
                                                             int* __restrict__ rowptr_last) {
    __shared__ int lds[256];
    int t = threadIdx.x;
    int v = (t < nb) ? blockSum[t] : 0;
    lds[t] = v;
    __syncthreads();
    for (int off = 1; off < 256; off <<= 1) {
        int u = (t >= off) ? lds[t - off] : 0;
        __syncthreads();
        lds[t] += u;
        __syncthreads();
    }
    if (t < nb) blockOff[t] = lds[t] - v;  // exclusive
    if (t == 255) *rowptr_last = lds[255];
}

// deg and cursor may alias (each thread touches only index i; reads precede writes)
__global__ __launch_bounds__(256) void block_scan_kernel(const int* deg,
                                                         const int* __restrict__ blockOff,
                                                         int* __restrict__ row_ptr,
                                                         int* cursor, int n) {
    __shared__ int lds[256];
    int t = threadIdx.x;
    int i = blockIdx.x * 256 + t;
    int v = (i < n) ? deg[i] : 0;
    lds[t] = v;
    __syncthreads();
    for (int off = 1; off < 256; off <<= 1) {
        int u = (t >= off) ? lds[t - off] : 0;
        __syncthreads();
        lds[t] += u;
        __syncthreads();
    }
    if (i < n) {
        int ex = blockOff[blockIdx.x] + lds[t] - v;
        row_ptr[i] = ex;
        cursor[i] = ex;
    }
}

__global__ void fill_csr_kernel(const int* __restrict__ ei, const float* __restrict__ ew,
                                int* __restrict__ cursor, int2* __restrict__ csr_sw, int E) {
    int e = blockIdx.x * blockDim.x + threadIdx.x;
    if (e >= E) return;
    int d = ei[E + e];
    int s = ei[e];
    if ((unsigned)d >= (unsigned)NN || (unsigned)s >= (unsigned)NN) return;
    int pos = atomicAdd(&cursor[d], 1);
    if (pos < E) csr_sw[pos] = make_int2(s, __float_as_int(ew[e]));
}

// ---------------- weight prep: transpose + hi/lo bf16 split ----------------
__global__ void wsplit_kernel(const float* __restrict__ w, u16* __restrict__ hiT,
                              u16* __restrict__ loT, int din, int dout) {
    int i = blockIdx.x * 256 + threadIdx.x;
    if (i >= din * dout) return;
    int k = i / dout, n = i - k * dout;
    float v = w[i];
    u16 h = f2bf(v);
    hiT[(size_t)n * din + k] = h;
    loT[(size_t)n * din + k] = f2bf(v - bf2f(h));
}

// w1_2 (256x40) -> padded transposed [64][256]
__global__ void wsplit_pad_kernel(const float* __restrict__ w, u16* __restrict__ hiT,
                                  u16* __restrict__ loT) {
    int i = blockIdx.x * 256 + threadIdx.x;
    if (i >= 64 * 256) return;
    int n = i >> 8, k = i & 255;
    float v = (n < 40) ? w[k * 40 + n] : 0.f;
    u16 h = f2bf(v);
    hiT[i] = h;
    loT[i] = f2bf(v - bf2f(h));
}

// ---------------- pull aggregation: out[n] = x[n] + sum_e w_e * x[src_e] ----------------
// Packed activation layout: [node][2][C] u16 (hi plane, lo plane), row stride 2C.
// Combos used: (128,fp32-in,packed-out), (256,packed-in,packed-out), (40,fp32-in,fp32-out).
template <int C, int INHL, int OUTHL>
__global__ __launch_bounds__(256) void aggregate_kernel(
    const float* __restrict__ xf, const u16* __restrict__ xp,
    const int* __restrict__ row_ptr, const int2* __restrict__ csw,
    float* __restrict__ outf, u16* __restrict__ outp, int n) {
    constexpr int V = (C == 128) ? 2 : 4;
    int node = blockIdx.x * 4 + (threadIdx.x >> 6);
    if (node >= n) return;
    int lane = threadIdx.x & 63;
    if (C == 40 && lane >= 10) return;
    int col = lane * V;
    int beg = row_ptr[node], end = row_ptr[node + 1];

    float acc[V];
    // ---- self term (eps = 0) ----
    if constexpr (INHL) {
        size_t b = (size_t)node * (2 * C) + col;
        ushort4 h = *(const ushort4*)(xp + b);
        ushort4 l = *(const ushort4*)(xp + b + C);
        acc[0] = bf2f(h.x) + bf2f(l.x); acc[1] = bf2f(h.y) + bf2f(l.y);
        acc[2] = bf2f(h.z) + bf2f(l.z); acc[3] = bf2f(h.w) + bf2f(l.w);
    } else if constexpr (V == 2) {
        float2 v = *(const float2*)(xf + (size_t)node * C + col);
        acc[0] = v.x; acc[1] = v.y;
    } else {
        float4 v = *(const float4*)(xf + (size_t)node * C + col);
        acc[0] = v.x; acc[1] = v.y; acc[2] = v.z; acc[3] = v.w;
    }

    // ---- 4x-unrolled edge loop: batch loads first (8 gathers in flight), then FMA ----
    int e = beg;
    for (; e + 4 <= end; e += 4) {
        int2 sw[4];
#pragma unroll
        for (int u = 0; u < 4; u++) sw[u] = csw[e + u];
        if constexpr (INHL) {
            ushort4 H[4], L[4];
#pragma unroll
            for (int u = 0; u < 4; u++) {
                size_t b = (size_t)sw[u].x * (2 * C) + col;
                H[u] = *(const ushort4*)(xp + b);
                L[u] = *(const ushort4*)(xp + b + C);
            }
#pragma unroll
            for (int u = 0; u < 4; u++) {
                float w = __int_as_float(sw[u].y);
                acc[0] = fmaf(w, bf2f(H[u].x) + bf2f(L[u].x), acc[0]);
                acc[1] = fmaf(w, bf2f(H[u].y) + bf2f(L[u].y), acc[1]);
                acc[2] = fmaf(w, bf2f(H[u].z) + bf2f(L[u].z), acc[2]);
                acc[3] = fmaf(w, bf2f(H[u].w) + bf2f(L[u].w), acc[3]);
            }
        } else if constexpr (V == 2) {
            float2 T[4];
#pragma unroll
            for (int u = 0; u < 4; u++) T[u] = *(const float2*)(xf + (size_t)sw[u].x * C + col);
#pragma unroll
            for (int u = 0; u < 4; u++) {
                float w = __int_as_float(sw[u].y);
                acc[0] = fmaf(w, T[u].x, acc[0]);
                acc[1] = fmaf(w, T[u].y, acc[1]);
            }
        } else {
            float4 T[4];
#pragma unroll
            for (int u = 0; u < 4; u++) T[u] = *(const float4*)(xf + (size_t)sw[u].x * C + col);
#pragma unroll
            for (int u = 0; u < 4; u++) {
                float w = __int_as_float(sw[u].y);
                acc[0] = fmaf(w, T[u].x, acc[0]); acc[1] = fmaf(w, T[u].y, acc[1]);
                acc[2] = fmaf(w, T[u].z, acc[2]); acc[3] = fmaf(w, T[u].w, acc[3]);
            }
        }
    }
    for (; e < end; ++e) {
        int2 sw = csw[e];
        float w = __int_as_float(sw.y);
        if constexpr (INHL) {
            size_t b = (size_t)sw.x * (2 * C) + col;
            ushort4 h = *(const ushort4*)(xp + b);
            ushort4 l = *(const ushort4*)(xp + b + C);
            acc[0] = fmaf(w, bf2f(h.x) + bf2f(l.x), acc[0]);
            acc[1] = fmaf(w, bf2f(h.y) + bf2f(l.y), acc[1]);
            acc[2] = fmaf(w, bf2f(h.z) + bf2f(l.z), acc[2]);
            acc[3] = fmaf(w, bf2f(h.w) + bf2f(l.w), acc[3]);
        } else if constexpr (V == 2) {
            float2 v = *(const float2*)(xf + (size_t)sw.x * C + col);
            acc[0] = fmaf(w, v.x, acc[0]); acc[1] = fmaf(w, v.y, acc[1]);
        } else {
            float4 v = *(const float4*)(xf + (size_t)sw.x * C + col);
            acc[0] = fmaf(w, v.x, acc[0]); acc[1] = fmaf(w, v.y, acc[1]);
            acc[2] = fmaf(w, v.z, acc[2]); acc[3] = fmaf(w, v.w, acc[3]);
        }
    }

    // ---- store ----
    if constexpr (OUTHL) {
        size_t ob = (size_t)node * (2 * C) + col;
        if constexpr (V == 2) {
            ushort2 h, l;
            h.x = f2bf(acc[0]); l.x = f2bf(acc[0] - bf2f(h.x));
            h.y = f2bf(acc[1]); l.y = f2bf(acc[1] - bf2f(h.y));
            *(ushort2*)(outp + ob) = h;
            *(ushort2*)(outp + ob + C) = l;
        } else {
            ushort4 h, l;
            h.x = f2bf(acc[0]); l.x = f2bf(acc[0] - bf2f(h.x));
            h.y = f2bf(acc[1]); l.y = f2bf(acc[1] - bf2f(h.y));
            h.z = f2bf(acc[2]); l.z = f2bf(acc[2] - bf2f(h.z));
            h.w = f2bf(acc[3]); l.w = f2bf(acc[3] - bf2f(h.w));
            *(ushort4*)(outp + ob) = h;
            *(ushort4*)(outp + ob + C) = l;
        }
    } else {
        size_t ob = (size_t)node * C + col;
        if constexpr (V == 2) {
            *(float2*)(outf + ob) = make_float2(acc[0], acc[1]);
        } else {
            *(float4*)(outf + ob) = make_float4(acc[0], acc[1], acc[2], acc[3]);
        }
    }
}

// ---------------- split-bf16 MFMA GEMM: BK=64, XOR-swizzled linear LDS ----------------
// A: (hi,lo) bf16, row stride LDA (packed layout: Alo = Ahi + C).  B: (hi,lo) TRANSPOSED [N][K].
// BM=128. EPI: 0 none, 1 bias+relu, 2 bias+BN+relu. OUTHL: 1 -> packed pair, 0 -> fp32.
// LDS rows: 64 u16 = 128 B = 8 x 16B chunks. Swizzle byte ^= (row&7)<<4 on BOTH sides.
template <int BN_, int EPI, int OUTHL>
__global__ __launch_bounds__(256, 2) void gemm_mfma_kernel(
    const u16* __restrict__ Ahi, const u16* __restrict__ Alo,
    const u16* __restrict__ Bhi, const u16* __restrict__ Blo,
    float* __restrict__ outf, u16* __restrict__ outhi, u16* __restrict__ outlo,
    int M, int K, int LDA, int LDC, int NSTORE,
    const float* __restrict__ bias,
    const float* __restrict__ bng, const float* __restrict__ bnb,
    const float* __restrict__ bnm, const float* __restrict__ bnv) {
    constexpr int WGN = (BN_ == 128) ? 2 : 1;
    constexpr int WGM = 4 / WGN;
    constexpr int WTM = 128 / WGM;  // wave tile M: 64 or 32
    constexpr int MF = WTM / 16;    // 4 or 2
    constexpr int NF = 4;           // wave tile N = 64
    __shared__ __attribute__((aligned(16))) u16 Ahl[2][128][64];
    __shared__ __attribute__((aligned(16))) u16 Bhl[2][BN_][64];

    const int tid = threadIdx.x;
    const int lane = tid & 63;
    const int wid = tid >> 6;
    const int wm = wid / WGN, wn = wid % WGN;
    const int m0 = blockIdx.x * 128, n0 = blockIdx.y * BN_;
    const int ln = lane & 15, l4 = lane >> 4;

    f32x4 acc[MF][NF];
#pragma unroll
    for (int mi = 0; mi < MF; mi++)
#pragma unroll
        for (int ni = 0; ni < NF; ni++) acc[mi][ni] = (f32x4){0.f, 0.f, 0.f, 0.f};

    for (int k0 = 0; k0 < K; k0 += 64) {
        // stage A: [2 planes][128 rows][8 x 16B chunks] = 2048 chunks, 8 reps
#pragma unroll
        for (int rep = 0; rep < 8; rep++) {
            int idx = rep * 256 + tid;
            int plane = idx >> 10;
            int rc = idx & 1023;
            int row = rc >> 3, c16 = rc & 7;
            const u16* src = plane ? Alo : Ahi;
            int gm = m0 + row;
            if (gm > M - 1) gm = M - 1;
            uint4 v = *(const uint4*)(src + (size_t)gm * LDA + k0 + c16 * 8);
            int sb = (c16 * 16) ^ ((row & 7) << 4);
            *(uint4*)((char*)&Ahl[plane][row][0] + sb) = v;
        }
        // stage B: [2][BN_][8] = BN_*16 chunks, BN_/16 reps
#pragma unroll
        for (int rep = 0; rep < BN_ / 16; rep++) {
            int idx = rep * 256 + tid;
            int plane = idx / (BN_ * 8);
            int rc = idx % (BN_ * 8);
            int row = rc >> 3, c16 = rc & 7;
            const u16* src = plane ? Blo : Bhi;
            uint4 v = *(const uint4*)(src + (size_t)(n0 + row) * K + k0 + c16 * 8);
            int sb = (c16 * 16) ^ ((row & 7) << 4);
            *(uint4*)((char*)&Bhl[plane][row][0] + sb) = v;
        }
        __syncthreads();

#pragma unroll
        for (int kk = 0; kk < 2; kk++) {
            bf16x8 ah[MF], al[MF], bh[NF], bl[NF];
#pragma unroll
            for (int mi = 0; mi < MF; mi++) {
                int row = wm * WTM + mi * 16 + ln;
                int sb = (kk * 64 + l4 * 16) ^ ((row & 7) << 4);
                ah[mi] = *(const bf16x8*)((const char*)&Ahl[0][row][0] + sb);
                al[mi] = *(const bf16x8*)((const char*)&Ahl[1][row][0] + sb);
            }
#pragma unroll
            for (int ni = 0; ni < NF; ni++) {
                int row = wn * 64 + ni * 16 + ln;
                int sb = (kk * 64 + l4 * 16) ^ ((row & 7) << 4);
                bh[ni] = *(const bf16x8*)((const char*)&Bhl[0][row][0] + sb);
                bl[ni] = *(const bf16x8*)((const char*)&Bhl[1][row][0] + sb);
            }
#pragma unroll
            for (int mi = 0; mi < MF; mi++)
#pragma unroll
                for (int ni = 0; ni < NF; ni++) {
                    acc[mi][ni] = __builtin_amdgcn_mfma_f32_16x16x32_bf16(ah[mi], bh[ni], acc[mi][ni], 0, 0, 0);
                    acc[mi][ni] = __builtin_amdgcn_mfma_f32_16x16x32_bf16(ah[mi], bl[ni], acc[mi][ni], 0, 0, 0);
                    acc[mi][ni] = __builtin_amdgcn_mfma_f32_16x16x32_bf16(al[mi], bh[ni], acc[mi][ni], 0, 0, 0);
                }
        }
        __syncthreads();
    }

    // epilogue: C/D layout col=lane&15, row=(lane>>4)*4+reg
#pragma unroll
    for (int ni = 0; ni < NF; ni++) {
        int c = n0 + wn * 64 + ni * 16 + ln;
        float bb = 0.f, sc = 1.f, sh = 0.f;
        if constexpr (EPI >= 1) bb = bias[c];
        if constexpr (EPI == 2) {
            float s = bng[c] * rsqrtf(bnv[c] + BN_EPS);
            sc = s;
            sh = bnb[c] - bnm[c] * s;
        }
        bool cok = (c < NSTORE);
#pragma unroll
        for (int mi = 0; mi < MF; mi++) {
#pragma unroll
            for (int r = 0; r < 4; r++) {
                int row = m0 + wm * WTM + mi * 16 + l4 * 4 + r;
                if (row < M && cok) {
                    float v = acc[mi][ni][r] + bb;
                    if constexpr (EPI == 1) v = fmaxf(v, 0.f);
                    if constexpr (EPI == 2) v = fmaxf(fmaf(v, sc, sh), 0.f);
                    size_t o = (size_t)row * LDC + c;
                    if constexpr (OUTHL) {
                        u16 h = f2bf(v);
                        outhi[o] = h;
                        outlo[o] = f2bf(v - bf2f(h));
                    } else {
                        outf[o] = v;
                    }
                }
            }
        }
    }
}

// ---------------- tail: relu(agg + b1) @ w2 + b2 -> log_softmax ----------------
__global__ __launch_bounds__(256) void final_kernel(
    const float* __restrict__ aggp, const float* __restrict__ b1,
    const float* __restrict__ w2, const float* __restrict__ b2,
    float* __restrict__ out, int n) {
    __shared__ float sw[40 * 40];
    __shared__ float sb1[40], sb2[40];
    for (int i = threadIdx.x; i < 1600; i += 256) sw[i] = w2[i];
    if (threadIdx.x < 40) { sb1[threadIdx.x] = b1[threadIdx.x]; sb2[threadIdx.x] = b2[threadIdx.x]; }
    __syncthreads();
    int row = blockIdx.x * 256 + threadIdx.x;
    if (row >= n) return;
    const float* ar = aggp + (size_t)row * 40;
    float t[40];
#pragma unroll
    for (int k = 0; k < 40; k++) t[k] = fmaxf(ar[k] + sb1[k], 0.f);
    float y[40];
#pragma unroll
    for (int j = 0; j < 40; j++) y[j] = sb2[j];
    for (int k = 0; k < 40; k++) {
        float tk = t[k];
#pragma unroll
        for (int j = 0; j < 40; j++) y[j] = fmaf(tk, sw[k * 40 + j], y[j]);
    }
    float m = -1e30f;
#pragma unroll
    for (int j = 0; j < 40; j++) m = fmaxf(m, y[j]);
    float s = 0.f;
#pragma unroll
    for (int j = 0; j < 40; j++) s += expf(y[j] - m);
    float lse = m + logf(s);
    float* orow = out + (size_t)row * 40;
#pragma unroll
    for (int j = 0; j < 40; j++) orow[j] = y[j] - lse;
}

extern "C" void kernel_launch(void* const* d_in, const int* in_sizes, int n_in,
                              void* d_out, int out_size, void* d_ws, size_t ws_size,
                              hipStream_t stream) {
    const float* x    = (const float*)d_in[0];
    const int*   ei   = (const int*)d_in[1];  // int64 in ref -> int32 on device
    const float* ew   = (const float*)d_in[2];
    const float* w1_0 = (const float*)d_in[3],  *b1_0 = (const float*)d_in[4];
    const float* w2_0 = (const float*)d_in[5],  *b2_0 = (const float*)d_in[6];
    const float* w1_1 = (const float*)d_in[7],  *b1_1 = (const float*)d_in[8];
    const float* w2_1 = (const float*)d_in[9],  *b2_1 = (const float*)d_in[10];
    const float* w1_2 = (const float*)d_in[11], *b1_2 = (const float*)d_in[12];
    const float* w2_2 = (const float*)d_in[13], *b2_2 = (const float*)d_in[14];
    const float* bng0 = (const float*)d_in[15], *bnb0 = (const float*)d_in[16];
    const float* bnm0 = (const float*)d_in[17], *bnv0 = (const float*)d_in[18];
    const float* bng1 = (const float*)d_in[19], *bnb1 = (const float*)d_in[20];
    const float* bnm1 = (const float*)d_in[21], *bnv1 = (const float*)d_in[22];
    float* out = (float*)d_out;

    char* wsp = (char*)d_ws;
    size_t off = 0;
    auto alloc = [&](size_t bytes) -> char* {
        char* p = wsp + off;
        off += (bytes + 255) & ~(size_t)255;
        return p;
    };
    int*   cursor   = (int*)alloc((size_t)NN * sizeof(int));
    int*   row_ptr  = (int*)alloc((size_t)(NN + 1) * sizeof(int));
    int*   blockSum = (int*)alloc(256 * sizeof(int));
    int*   blockOff = (int*)alloc(256 * sizeof(int));
    int2*  csr_sw   = (int2*)alloc((size_t)NE * sizeof(int2));
    u16* bufP = (u16*)alloc((size_t)NN * 512 * sizeof(u16));  // packed [node][2][256]
    u16* bufQ = (u16*)alloc((size_t)NN * 512 * sizeof(u16));
    u16* w10h = (u16*)alloc(128 * 256 * 2); u16* w10l = (u16*)alloc(128 * 256 * 2);
    u16* w20h = (u16*)alloc(256 * 256 * 2); u16* w20l = (u16*)alloc(256 * 256 * 2);
    u16* w11h = (u16*)alloc(256 * 256 * 2); u16* w11l = (u16*)alloc(256 * 256 * 2);
    u16* w21h = (u16*)alloc(256 * 256 * 2); u16* w21l = (u16*)alloc(256 * 256 * 2);
    u16* wph  = (u16*)alloc(64 * 256 * 2);  u16* wpl  = (u16*)alloc(64 * 256 * 2);

    const int NB = (NN + 255) / 256;  // 196

    // --- CSR build (parallel scan) ---
    hipMemsetAsync(cursor, 0, (size_t)NN * sizeof(int), stream);
    count_deg_kernel<<<(NE + 255) / 256, 256, 0, stream>>>(ei, cursor, NE);
    block_reduce_kernel<<<NB, 256, 0, stream>>>(cursor, blockSum, NN);
    scan_blocksums_kernel<<<1, 256, 0, stream>>>(blockSum, blockOff, NB, row_ptr + NN);
    block_scan_kernel<<<NB, 256, 0, stream>>>(cursor, blockOff, row_ptr, cursor, NN);
    fill_csr_kernel<<<(NE + 255) / 256, 256, 0, stream>>>(ei, ew, cursor, csr_sw, NE);

    // --- weight prep ---
    wsplit_kernel<<<(128 * 256 + 255) / 256, 256, 0, stream>>>(w1_0, w10h, w10l, 128, 256);
    wsplit_kernel<<<(256 * 256 + 255) / 256, 256, 0, stream>>>(w2_0, w20h, w20l, 256, 256);
    wsplit_kernel<<<(256 * 256 + 255) / 256, 256, 0, stream>>>(w1_1, w11h, w11l, 256, 256);
    wsplit_kernel<<<(256 * 256 + 255) / 256, 256, 0, stream>>>(w2_1, w21h, w21l, 256, 256);
    wsplit_pad_kernel<<<64, 256, 0, stream>>>(w1_2, wph, wpl);

    const int aggBlocks = (NN + 3) / 4;
    dim3 gBig((NN + 127) / 128, 2);
    dim3 gSm((NN + 127) / 128, 1);

    // ---- layer 0 ----  (bufP: packed [node][2][128]; LDA=256)
    aggregate_kernel<128, 0, 1><<<aggBlocks, 256, 0, stream>>>(
        x, nullptr, row_ptr, csr_sw, nullptr, bufP, NN);
    gemm_mfma_kernel<128, 1, 1><<<gBig, 256, 0, stream>>>(
        bufP, bufP + 128, w10h, w10l, nullptr, bufQ, bufQ + 256, NN, 128, 256, 512, 256,
        b1_0, nullptr, nullptr, nullptr, nullptr);
    gemm_mfma_kernel<128, 2, 1><<<gBig, 256, 0, stream>>>(
        bufQ, bufQ + 256, w20h, w20l, nullptr, bufP, bufP + 256, NN, 256, 512, 512, 256,
        b2_0, bng0, bnb0, bnm0, bnv0);

    // ---- layer 1 ----
    aggregate_kernel<256, 1, 1><<<aggBlocks, 256, 0, stream>>>(
        nullptr, bufP, row_ptr, csr_sw, nullptr, bufQ, NN);
    gemm_mfma_kernel<128, 1, 1><<<gBig, 256, 0, stream>>>(
        bufQ, bufQ + 256, w11h, w11l, nullptr, bufP, bufP + 256, NN, 256, 512, 512, 256,
        b1_1, nullptr, nullptr, nullptr, nullptr);
    gemm_mfma_kernel<128, 2, 1><<<gBig, 256, 0, stream>>>(
        bufP, bufP + 256, w21h, w21l, nullptr, bufQ, bufQ + 256, NN, 256, 512, 512, 256,
        b2_1, bng1, bnb1, bnm1, bnv1);

    // ---- layer 2 (reordered: p = h @ w1_2 first, then aggregate 40 channels) ----
    float* p    = (float*)bufP;  // 8 MB, bufP free after L1 g2 read
    float* aggp = (float*)bufQ;  // bufQ free after L2 gemm read
    gemm_mfma_kernel<64, 0, 0><<<gSm, 256, 0, stream>>>(
        bufQ, bufQ + 256, wph, wpl, p, nullptr, nullptr, NN, 256, 512, 40, 40,
        nullptr, nullptr, nullptr, nullptr, nullptr);
    aggregate_kernel<40, 0, 0><<<aggBlocks, 256, 0, stream>>>(
        p, nullptr, row_ptr, csr_sw, aggp, nullptr, NN);
    final_kernel<<<NB, 256, 0, stream>>>(aggp, b1_2, w2_2, b2_2, out, NN);
}

// Round 7
// 505.362 us; speedup vs baseline: 1.7965x; 1.0988x over previous
//
#include <hip/hip_runtime.h>
#include <cstdint>
#include <cstddef>

#define BN_EPS 1e-5f

typedef unsigned short u16;
typedef __attribute__((ext_vector_type(8))) short bf16x8;   // 8 bf16 (4 VGPRs)
typedef __attribute__((ext_vector_type(4))) float f32x4;

constexpr int NN = 50000;
constexpr int NE = 800000;

__device__ __forceinline__ u16 f2bf(float f) {
    unsigned u = __float_as_uint(f);
    return (u16)((u + 0x7fffu + ((u >> 16) & 1u)) >> 16);   // RNE
}
__device__ __forceinline__ float bf2f(u16 h) { return __uint_as_float(((unsigned)h) << 16); }

// ---------------- CSR build (edge_index arrives as int32) ----------------
__global__ void count_deg_kernel(const int* __restrict__ ei, int* __restrict__ deg, int E) {
    int e = blockIdx.x * blockDim.x + threadIdx.x;
    if (e >= E) return;
    int d = ei[E + e];
    if ((unsigned)d < (unsigned)NN) atomicAdd(&deg[d], 1);
}

__global__ __launch_bounds__(256) void block_reduce_kernel(const int* __restrict__ deg,
                                                           int* __restrict__ blockSum, int n) {
    __shared__ int red[256];
    int i = blockIdx.x * 256 + threadIdx.x;
    red[threadIdx.x] = (i < n) ? deg[i] : 0;
    __syncthreads();
    for (int s = 128; s > 0; s >>= 1) {
        if (threadIdx.x < s) red[threadIdx.x] += red[threadIdx.x + s];
        __syncthreads();
    }
    if (threadIdx.x == 0) blockSum[blockIdx.x] = red[0];
}

__global__ __launch_bounds__(256) void scan_blocksums_kernel(const int* __restrict__ blockSum,
                                                             int* __restrict__ blockOff, int nb,
                                                             int* __restrict__ rowptr_last) {
    __shared__ int lds[256];
    int t = threadIdx.x;
    int v = (t < nb) ? blockSum[t] : 0;
    lds[t] = v;
    __syncthreads();
    for (int off = 1; off < 256; off <<= 1) {
        int u = (t >= off) ? lds[t - off] : 0;
        __syncthreads();
        lds[t] += u;
        __syncthreads();
    }
    if (t < nb) blockOff[t] = lds[t] - v;  // exclusive
    if (t == 255) *rowptr_last = lds[255];
}

// deg and cursor may alias (each thread touches only index i; reads precede writes)
__global__ __launch_bounds__(256) void block_scan_kernel(const int* deg,
                                                         const int* __restrict__ blockOff,
                                                         int* __restrict__ row_ptr,
                                                         int* cursor, int n) {
    __shared__ int lds[256];
    int t = threadIdx.x;
    int i = blockIdx.x * 256 + t;
    int v = (i < n) ? deg[i] : 0;
    lds[t] = v;
    __syncthreads();
    for (int off = 1; off < 256; off <<= 1) {
        int u = (t >= off) ? lds[t - off] : 0;
        __syncthreads();
        lds[t] += u;
        __syncthreads();
    }
    if (i < n) {
        int ex = blockOff[blockIdx.x] + lds[t] - v;
        row_ptr[i] = ex;
        cursor[i] = ex;
    }
}

__global__ void fill_csr_kernel(const int* __restrict__ ei, const float* __restrict__ ew,
                                int* __restrict__ cursor, int2* __restrict__ csr_sw, int E) {
    int e = blockIdx.x * blockDim.x + threadIdx.x;
    if (e >= E) return;
    int d = ei[E + e];
    int s = ei[e];
    if ((unsigned)d >= (unsigned)NN || (unsigned)s >= (unsigned)NN) return;
    int pos = atomicAdd(&cursor[d], 1);
    if (pos < E) csr_sw[pos] = make_int2(s, __float_as_int(ew[e]));
}

// ---------------- weight prep: transpose + hi/lo bf16 split ----------------
__global__ void wsplit_kernel(const float* __restrict__ w, u16* __restrict__ hiT,
                              u16* __restrict__ loT, int din, int dout) {
    int i = blockIdx.x * 256 + threadIdx.x;
    if (i >= din * dout) return;
    int k = i / dout, n = i - k * dout;
    float v = w[i];
    u16 h = f2bf(v);
    hiT[(size_t)n * din + k] = h;
    loT[(size_t)n * din + k] = f2bf(v - bf2f(h));
}

// w1_2 (256x40) -> padded transposed [64][256]
__global__ void wsplit_pad_kernel(const float* __restrict__ w, u16* __restrict__ hiT,
                                  u16* __restrict__ loT) {
    int i = blockIdx.x * 256 + threadIdx.x;
    if (i >= 64 * 256) return;
    int n = i >> 8, k = i & 255;
    float v = (n < 40) ? w[k * 40 + n] : 0.f;
    u16 h = f2bf(v);
    hiT[i] = h;
    loT[i] = f2bf(v - bf2f(h));
}

// ---------------- pull aggregation: out[n] = x[n] + sum_e w_e * x[src_e] ----------------
// Per-C semantics (fixed combos):
//   C=128: self fp32 xf, gather fp32 xf (exact), out packed [node][2][128]
//   C=256: self packed xp (hi+lo), gather HI PLANE ONLY (bf16), out packed [node][2][256]
//   C=40 : self fp32 xf, gather bf16 xb, out fp32
template <int C>
__global__ __launch_bounds__(256) void aggregate_kernel(
    const float* __restrict__ xf, const u16* __restrict__ xp, const u16* __restrict__ xb,
    const int* __restrict__ row_ptr, const int2* __restrict__ csw,
    float* __restrict__ outf, u16* __restrict__ outp, int n) {
    constexpr int V = (C == 128) ? 2 : 4;
    int node = blockIdx.x * 4 + (threadIdx.x >> 6);
    if (node >= n) return;
    int lane = threadIdx.x & 63;
    if (C == 40 && lane >= 10) return;
    int col = lane * V;
    int beg = row_ptr[node], end = row_ptr[node + 1];

    float acc[V];
    // ---- self term (eps = 0), always full precision ----
    if constexpr (C == 128) {
        float2 v = *(const float2*)(xf + (size_t)node * C + col);
        acc[0] = v.x; acc[1] = v.y;
    } else if constexpr (C == 256) {
        size_t b = (size_t)node * (2 * C) + col;
        ushort4 h = *(const ushort4*)(xp + b);
        ushort4 l = *(const ushort4*)(xp + b + C);
        acc[0] = bf2f(h.x) + bf2f(l.x); acc[1] = bf2f(h.y) + bf2f(l.y);
        acc[2] = bf2f(h.z) + bf2f(l.z); acc[3] = bf2f(h.w) + bf2f(l.w);
    } else {
        float4 v = *(const float4*)(xf + (size_t)node * C + col);
        acc[0] = v.x; acc[1] = v.y; acc[2] = v.z; acc[3] = v.w;
    }

    // ---- 4x-unrolled edge loop: batch loads first, then FMA ----
    int e = beg;
    for (; e + 4 <= end; e += 4) {
        int2 sw[4];
#pragma unroll
        for (int u = 0; u < 4; u++) sw[u] = csw[e + u];
        if constexpr (C == 128) {
            float2 T[4];
#pragma unroll
            for (int u = 0; u < 4; u++) T[u] = *(const float2*)(xf + (size_t)sw[u].x * C + col);
#pragma unroll
            for (int u = 0; u < 4; u++) {
                float w = __int_as_float(sw[u].y);
                acc[0] = fmaf(w, T[u].x, acc[0]);
                acc[1] = fmaf(w, T[u].y, acc[1]);
            }
        } else if constexpr (C == 256) {
            ushort4 H[4];
#pragma unroll
            for (int u = 0; u < 4; u++) H[u] = *(const ushort4*)(xp + (size_t)sw[u].x * (2 * C) + col);
#pragma unroll
            for (int u = 0; u < 4; u++) {
                float w = __int_as_float(sw[u].y);
                acc[0] = fmaf(w, bf2f(H[u].x), acc[0]);
                acc[1] = fmaf(w, bf2f(H[u].y), acc[1]);
                acc[2] = fmaf(w, bf2f(H[u].z), acc[2]);
                acc[3] = fmaf(w, bf2f(H[u].w), acc[3]);
            }
        } else {
            ushort4 H[4];
#pragma unroll
            for (int u = 0; u < 4; u++) H[u] = *(const ushort4*)(xb + (size_t)sw[u].x * C + col);
#pragma unroll
            for (int u = 0; u < 4; u++) {
                float w = __int_as_float(sw[u].y);
                acc[0] = fmaf(w, bf2f(H[u].x), acc[0]);
                acc[1] = fmaf(w, bf2f(H[u].y), acc[1]);
                acc[2] = fmaf(w, bf2f(H[u].z), acc[2]);
                acc[3] = fmaf(w, bf2f(H[u].w), acc[3]);
            }
        }
    }
    for (; e < end; ++e) {
        int2 sw = csw[e];
        float w = __int_as_float(sw.y);
        if constexpr (C == 128) {
            float2 v = *(const float2*)(xf + (size_t)sw.x * C + col);
            acc[0] = fmaf(w, v.x, acc[0]); acc[1] = fmaf(w, v.y, acc[1]);
        } else if constexpr (C == 256) {
            ushort4 h = *(const ushort4*)(xp + (size_t)sw.x * (2 * C) + col);
            acc[0] = fmaf(w, bf2f(h.x), acc[0]); acc[1] = fmaf(w, bf2f(h.y), acc[1]);
            acc[2] = fmaf(w, bf2f(h.z), acc[2]); acc[3] = fmaf(w, bf2f(h.w), acc[3]);
        } else {
            ushort4 h = *(const ushort4*)(xb + (size_t)sw.x * C + col);
            acc[0] = fmaf(w, bf2f(h.x), acc[0]); acc[1] = fmaf(w, bf2f(h.y), acc[1]);
            acc[2] = fmaf(w, bf2f(h.z), acc[2]); acc[3] = fmaf(w, bf2f(h.w), acc[3]);
        }
    }

    // ---- store ----
    if constexpr (C == 128) {
        size_t ob = (size_t)node * (2 * C) + col;
        ushort2 h, l;
        h.x = f2bf(acc[0]); l.x = f2bf(acc[0] - bf2f(h.x));
        h.y = f2bf(acc[1]); l.y = f2bf(acc[1] - bf2f(h.y));
        *(ushort2*)(outp + ob) = h;
        *(ushort2*)(outp + ob + C) = l;
    } else if constexpr (C == 256) {
        size_t ob = (size_t)node * (2 * C) + col;
        ushort4 h, l;
        h.x = f2bf(acc[0]); l.x = f2bf(acc[0] - bf2f(h.x));
        h.y = f2bf(acc[1]); l.y = f2bf(acc[1] - bf2f(h.y));
        h.z = f2bf(acc[2]); l.z = f2bf(acc[2] - bf2f(h.z));
        h.w = f2bf(acc[3]); l.w = f2bf(acc[3] - bf2f(h.w));
        *(ushort4*)(outp + ob) = h;
        *(ushort4*)(outp + ob + C) = l;
    } else {
        size_t ob = (size_t)node * C + col;
        *(float4*)(outf + ob) = make_float4(acc[0], acc[1], acc[2], acc[3]);
    }
}

// ---------------- split-bf16 MFMA GEMM: BK=64, XOR-swizzled linear LDS ----------------
// A: (hi,lo) bf16, row stride LDA (packed layout: Alo = Ahi + C).  B: (hi,lo) TRANSPOSED [N][K].
// BM=128. EPI: 0 none, 1 bias+relu, 2 bias+BN+relu.
// OUTHL: 0 -> fp32; 1 -> packed (hi,lo) pair; 2 -> fp32 (outf) + bf16 copy (outhi).
// LDS rows: 64 u16 = 128 B = 8 x 16B chunks. Swizzle byte ^= (row&7)<<4 on BOTH sides.
template <int BN_, int EPI, int OUTHL>
__global__ __launch_bounds__(256, 2) void gemm_mfma_kernel(
    const u16* __restrict__ Ahi, const u16* __restrict__ Alo,
    const u16* __restrict__ Bhi, const u16* __restrict__ Blo,
    float* __restrict__ outf, u16* __restrict__ outhi, u16* __restrict__ outlo,
    int M, int K, int LDA, int LDC, int NSTORE,
    const float* __restrict__ bias,
    const float* __restrict__ bng, const float* __restrict__ bnb,
    const float* __restrict__ bnm, const float* __restrict__ bnv) {
    constexpr int WGN = (BN_ == 128) ? 2 : 1;
    constexpr int WGM = 4 / WGN;
    constexpr int WTM = 128 / WGM;  // wave tile M: 64 or 32
    constexpr int MF = WTM / 16;    // 4 or 2
    constexpr int NF = 4;           // wave tile N = 64
    __shared__ __attribute__((aligned(16))) u16 Ahl[2][128][64];
    __shared__ __attribute__((aligned(16))) u16 Bhl[2][BN_][64];

    const int tid = threadIdx.x;
    const int lane = tid & 63;
    const int wid = tid >> 6;
    const int wm = wid / WGN, wn = wid % WGN;
    const int m0 = blockIdx.x * 128, n0 = blockIdx.y * BN_;
    const int ln = lane & 15, l4 = lane >> 4;

    f32x4 acc[MF][NF];
#pragma unroll
    for (int mi = 0; mi < MF; mi++)
#pragma unroll
        for (int ni = 0; ni < NF; ni++) acc[mi][ni] = (f32x4){0.f, 0.f, 0.f, 0.f};

    for (int k0 = 0; k0 < K; k0 += 64) {
        // stage A: [2 planes][128 rows][8 x 16B chunks] = 2048 chunks, 8 reps
#pragma unroll
        for (int rep = 0; rep < 8; rep++) {
            int idx = rep * 256 + tid;
            int plane = idx >> 10;
            int rc = idx & 1023;
            int row = rc >> 3, c16 = rc & 7;
            const u16* src = plane ? Alo : Ahi;
            int gm = m0 + row;
            if (gm > M - 1) gm = M - 1;
            uint4 v = *(const uint4*)(src + (size_t)gm * LDA + k0 + c16 * 8);
            int sb = (c16 * 16) ^ ((row & 7) << 4);
            *(uint4*)((char*)&Ahl[plane][row][0] + sb) = v;
        }
        // stage B: [2][BN_][8] = BN_*16 chunks, BN_/16 reps
#pragma unroll
        for (int rep = 0; rep < BN_ / 16; rep++) {
            int idx = rep * 256 + tid;
            int plane = idx / (BN_ * 8);
            int rc = idx % (BN_ * 8);
            int row = rc >> 3, c16 = rc & 7;
            const u16* src = plane ? Blo : Bhi;
            uint4 v = *(const uint4*)(src + (size_t)(n0 + row) * K + k0 + c16 * 8);
            int sb = (c16 * 16) ^ ((row & 7) << 4);
            *(uint4*)((char*)&Bhl[plane][row][0] + sb) = v;
        }
        __syncthreads();

#pragma unroll
        for (int kk = 0; kk < 2; kk++) {
            bf16x8 ah[MF], al[MF], bh[NF], bl[NF];
#pragma unroll
            for (int mi = 0; mi < MF; mi++) {
                int row = wm * WTM + mi * 16 + ln;
                int sb = (kk * 64 + l4 * 16) ^ ((row & 7) << 4);
                ah[mi] = *(const bf16x8*)((const char*)&Ahl[0][row][0] + sb);
                al[mi] = *(const bf16x8*)((const char*)&Ahl[1][row][0] + sb);
            }
#pragma unroll
            for (int ni = 0; ni < NF; ni++) {
                int row = wn * 64 + ni * 16 + ln;
                int sb = (kk * 64 + l4 * 16) ^ ((row & 7) << 4);
                bh[ni] = *(const bf16x8*)((const char*)&Bhl[0][row][0] + sb);
                bl[ni] = *(const bf16x8*)((const char*)&Bhl[1][row][0] + sb);
            }
#pragma unroll
            for (int mi = 0; mi < MF; mi++)
#pragma unroll
                for (int ni = 0; ni < NF; ni++) {
                    acc[mi][ni] = __builtin_amdgcn_mfma_f32_16x16x32_bf16(ah[mi], bh[ni], acc[mi][ni], 0, 0, 0);
                    acc[mi][ni] = __builtin_amdgcn_mfma_f32_16x16x32_bf16(ah[mi], bl[ni], acc[mi][ni], 0, 0, 0);
                    acc[mi][ni] = __builtin_amdgcn_mfma_f32_16x16x32_bf16(al[mi], bh[ni], acc[mi][ni], 0, 0, 0);
                }
        }
        __syncthreads();
    }

    // epilogue: C/D layout col=lane&15, row=(lane>>4)*4+reg
#pragma unroll
    for (int ni = 0; ni < NF; ni++) {
        int c = n0 + wn * 64 + ni * 16 + ln;
        float bb = 0.f, sc = 1.f, sh = 0.f;
        if constexpr (EPI >= 1) bb = bias[c];
        if constexpr (EPI == 2) {
            float s = bng[c] * rsqrtf(bnv[c] + BN_EPS);
            sc = s;
            sh = bnb[c] - bnm[c] * s;
        }
        bool cok = (c < NSTORE);
#pragma unroll
        for (int mi = 0; mi < MF; mi++) {
#pragma unroll
            for (int r = 0; r < 4; r++) {
                int row = m0 + wm * WTM + mi * 16 + l4 * 4 + r;
                if (row < M && cok) {
                    float v = acc[mi][ni][r] + bb;
                    if constexpr (EPI == 1) v = fmaxf(v, 0.f);
                    if constexpr (EPI == 2) v = fmaxf(fmaf(v, sc, sh), 0.f);
                    size_t o = (size_t)row * LDC + c;
                    if constexpr (OUTHL == 1) {
                        u16 h = f2bf(v);
                        outhi[o] = h;
                        outlo[o] = f2bf(v - bf2f(h));
                    } else if constexpr (OUTHL == 2) {
                        outf[o] = v;
                        outhi[o] = f2bf(v);
                    } else {
                        outf[o] = v;
                    }
                }
            }
        }
    }
}

// ---------------- tail: relu(agg + b1) @ w2 + b2 -> log_softmax ----------------
__global__ __launch_bounds__(256) void final_kernel(
    const float* __restrict__ aggp, const float* __restrict__ b1,
    const float* __restrict__ w2, const float* __restrict__ b2,
    float* __restrict__ out, int n) {
    __shared__ float sw[40 * 40];
    __shared__ float sb1[40], sb2[40];
    for (int i = threadIdx.x; i < 1600; i += 256) sw[i] = w2[i];
    if (threadIdx.x < 40) { sb1[threadIdx.x] = b1[threadIdx.x]; sb2[threadIdx.x] = b2[threadIdx.x]; }
    __syncthreads();
    int row = blockIdx.x * 256 + threadIdx.x;
    if (row >= n) return;
    const float* ar = aggp + (size_t)row * 40;
    float t[40];
#pragma unroll
    for (int k = 0; k < 40; k++) t[k] = fmaxf(ar[k] + sb1[k], 0.f);
    float y[40];
#pragma unroll
    for (int j = 0; j < 40; j++) y[j] = sb2[j];
    for (int k = 0; k < 40; k++) {
        float tk = t[k];
#pragma unroll
        for (int j = 0; j < 40; j++) y[j] = fmaf(tk, sw[k * 40 + j], y[j]);
    }
    float m = -1e30f;
#pragma unroll
    for (int j = 0; j < 40; j++) m = fmaxf(m, y[j]);
    float s = 0.f;
#pragma unroll
    for (int j = 0; j < 40; j++) s += expf(y[j] - m);
    float lse = m + logf(s);
    float* orow = out + (size_t)row * 40;
#pragma unroll
    for (int j = 0; j < 40; j++) orow[j] = y[j] - lse;
}

extern "C" void kernel_launch(void* const* d_in, const int* in_sizes, int n_in,
                              void* d_out, int out_size, void* d_ws, size_t ws_size,
                              hipStream_t stream) {
    const float* x    = (const float*)d_in[0];
    const int*   ei   = (const int*)d_in[1];  // int64 in ref -> int32 on device
    const float* ew   = (const float*)d_in[2];
    const float* w1_0 = (const float*)d_in[3],  *b1_0 = (const float*)d_in[4];
    const float* w2_0 = (const float*)d_in[5],  *b2_0 = (const float*)d_in[6];
    const float* w1_1 = (const float*)d_in[7],  *b1_1 = (const float*)d_in[8];
    const float* w2_1 = (const float*)d_in[9],  *b2_1 = (const float*)d_in[10];
    const float* w1_2 = (const float*)d_in[11], *b1_2 = (const float*)d_in[12];
    const float* w2_2 = (const float*)d_in[13], *b2_2 = (const float*)d_in[14];
    const float* bng0 = (const float*)d_in[15], *bnb0 = (const float*)d_in[16];
    const float* bnm0 = (const float*)d_in[17], *bnv0 = (const float*)d_in[18];
    const float* bng1 = (const float*)d_in[19], *bnb1 = (const float*)d_in[20];
    const float* bnm1 = (const float*)d_in[21], *bnv1 = (const float*)d_in[22];
    float* out = (float*)d_out;

    char* wsp = (char*)d_ws;
    size_t off = 0;
    auto alloc = [&](size_t bytes) -> char* {
        char* p = wsp + off;
        off += (bytes + 255) & ~(size_t)255;
        return p;
    };
    int*   cursor   = (int*)alloc((size_t)NN * sizeof(int));
    int*   row_ptr  = (int*)alloc((size_t)(NN + 1) * sizeof(int));
    int*   blockSum = (int*)alloc(256 * sizeof(int));
    int*   blockOff = (int*)alloc(256 * sizeof(int));
    int2*  csr_sw   = (int2*)alloc((size_t)NE * sizeof(int2));
    u16* bufP = (u16*)alloc((size_t)NN * 512 * sizeof(u16));  // packed [node][2][256]
    u16* bufQ = (u16*)alloc((size_t)NN * 512 * sizeof(u16));
    u16* w10h = (u16*)alloc(128 * 256 * 2); u16* w10l = (u16*)alloc(128 * 256 * 2);
    u16* w20h = (u16*)alloc(256 * 256 * 2); u16* w20l = (u16*)alloc(256 * 256 * 2);
    u16* w11h = (u16*)alloc(256 * 256 * 2); u16* w11l = (u16*)alloc(256 * 256 * 2);
    u16* w21h = (u16*)alloc(256 * 256 * 2); u16* w21l = (u16*)alloc(256 * 256 * 2);
    u16* wph  = (u16*)alloc(64 * 256 * 2);  u16* wpl  = (u16*)alloc(64 * 256 * 2);

    const int NB = (NN + 255) / 256;  // 196

    // --- CSR build (parallel scan) ---
    hipMemsetAsync(cursor, 0, (size_t)NN * sizeof(int), stream);
    count_deg_kernel<<<(NE + 255) / 256, 256, 0, stream>>>(ei, cursor, NE);
    block_reduce_kernel<<<NB, 256, 0, stream>>>(cursor, blockSum, NN);
    scan_blocksums_kernel<<<1, 256, 0, stream>>>(blockSum, blockOff, NB, row_ptr + NN);
    block_scan_kernel<<<NB, 256, 0, stream>>>(cursor, blockOff, row_ptr, cursor, NN);
    fill_csr_kernel<<<(NE + 255) / 256, 256, 0, stream>>>(ei, ew, cursor, csr_sw, NE);

    // --- weight prep ---
    wsplit_kernel<<<(128 * 256 + 255) / 256, 256, 0, stream>>>(w1_0, w10h, w10l, 128, 256);
    wsplit_kernel<<<(256 * 256 + 255) / 256, 256, 0, stream>>>(w2_0, w20h, w20l, 256, 256);
    wsplit_kernel<<<(256 * 256 + 255) / 256, 256, 0, stream>>>(w1_1, w11h, w11l, 256, 256);
    wsplit_kernel<<<(256 * 256 + 255) / 256, 256, 0, stream>>>(w2_1, w21h, w21l, 256, 256);
    wsplit_pad_kernel<<<64, 256, 0, stream>>>(w1_2, wph, wpl);

    const int aggBlocks = (NN + 3) / 4;
    dim3 gBig((NN + 127) / 128, 2);
    dim3 gSm((NN + 127) / 128, 1);

    // ---- layer 0 ----  (bufP: packed [node][2][128]; LDA=256)
    aggregate_kernel<128><<<aggBlocks, 256, 0, stream>>>(
        x, nullptr, nullptr, row_ptr, csr_sw, nullptr, bufP, NN);
    gemm_mfma_kernel<128, 1, 1><<<gBig, 256, 0, stream>>>(
        bufP, bufP + 128, w10h, w10l, nullptr, bufQ, bufQ + 256, NN, 128, 256, 512, 256,
        b1_0, nullptr, nullptr, nullptr, nullptr);
    gemm_mfma_kernel<128, 2, 1><<<gBig, 256, 0, stream>>>(
        bufQ, bufQ + 256, w20h, w20l, nullptr, bufP, bufP + 256, NN, 256, 512, 512, 256,
        b2_0, bng0, bnb0, bnm0, bnv0);

    // ---- layer 1 ---- (agg gathers HI plane only)
    aggregate_kernel<256><<<aggBlocks, 256, 0, stream>>>(
        nullptr, bufP, nullptr, row_ptr, csr_sw, nullptr, bufQ, NN);
    gemm_mfma_kernel<128, 1, 1><<<gBig, 256, 0, stream>>>(
        bufQ, bufQ + 256, w11h, w11l, nullptr, bufP, bufP + 256, NN, 256, 512, 512, 256,
        b1_1, nullptr, nullptr, nullptr, nullptr);
    gemm_mfma_kernel<128, 2, 1><<<gBig, 256, 0, stream>>>(
        bufP, bufP + 256, w21h, w21l, nullptr, bufQ, bufQ + 256, NN, 256, 512, 512, 256,
        b2_1, bng1, bnb1, bnm1, bnv1);

    // ---- layer 2 (reordered: p = h @ w1_2 first, then aggregate 40 channels) ----
    // bufP free after L1 g2: p fp32 in [0, 8MB), pbf bf16 in [8MB, 12MB)
    float* p    = (float*)bufP;
    u16*   pbf  = bufP + 4000000;            // 8 MB offset in u16 elements
    float* aggp = (float*)bufQ;              // bufQ free after L2 gemm reads it
    gemm_mfma_kernel<64, 0, 2><<<gSm, 256, 0, stream>>>(
        bufQ, bufQ + 256, wph, wpl, p, pbf, nullptr, NN, 256, 512, 40, 40,
        nullptr, nullptr, nullptr, nullptr, nullptr);
    aggregate_kernel<40><<<aggBlocks, 256, 0, stream>>>(
        p, nullptr, pbf, row_ptr, csr_sw, aggp, nullptr, NN);
    final_kernel<<<NB, 256, 0, stream>>>(aggp, b1_2, w2_2, b2_2, out, NN);
}

// Round 8
// 498.411 us; speedup vs baseline: 1.8215x; 1.0139x over previous
//
#include <hip/hip_runtime.h>
#include <cstdint>
#include <cstddef>

#define BN_EPS 1e-5f

typedef unsigned short u16;
typedef __attribute__((ext_vector_type(8))) short bf16x8;   // 8 bf16 (4 VGPRs)
typedef __attribute__((ext_vector_type(4))) float f32x4;

constexpr int NN = 50000;
constexpr int NE = 800000;

__device__ __forceinline__ u16 f2bf(float f) {
    unsigned u = __float_as_uint(f);
    return (u16)((u + 0x7fffu + ((u >> 16) & 1u)) >> 16);   // RNE
}
__device__ __forceinline__ float bf2f(u16 h) { return __uint_as_float(((unsigned)h) << 16); }

// async global->LDS 16B DMA. LDS dest = wave-uniform base + lane*16 (m104);
// global source is per-lane. Swizzle lives in producers + ds_read (rule #21).
__device__ __forceinline__ void gload16(const u16* g, u16* l) {
    __builtin_amdgcn_global_load_lds(
        (const __attribute__((address_space(1))) void*)g,
        (__attribute__((address_space(3))) void*)l, 16, 0, 0);
}

// u16-index XOR swizzle within a 64-u16 (128 B) group; row&7 spreads banks.
__device__ __forceinline__ int swz(int col_u16, int row) {
    return col_u16 ^ ((row & 7) << 3);
}

// ---------------- CSR build (edge_index arrives as int32) ----------------
__global__ void count_deg_kernel(const int* __restrict__ ei, int* __restrict__ deg, int E) {
    int e = blockIdx.x * blockDim.x + threadIdx.x;
    if (e >= E) return;
    int d = ei[E + e];
    if ((unsigned)d < (unsigned)NN) atomicAdd(&deg[d], 1);
}

__global__ __launch_bounds__(256) void block_reduce_kernel(const int* __restrict__ deg,
                                                           int* __restrict__ blockSum, int n) {
    __shared__ int red[256];
    int i = blockIdx.x * 256 + threadIdx.x;
    red[threadIdx.x] = (i < n) ? deg[i] : 0;
    __syncthreads();
    for (int s = 128; s > 0; s >>= 1) {
        if (threadIdx.x < s) red[threadIdx.x] += red[threadIdx.x + s];
        __syncthreads();
    }
    if (threadIdx.x == 0) blockSum[blockIdx.x] = red[0];
}

__global__ __launch_bounds__(256) void scan_blocksums_kernel(const int* __restrict__ blockSum,
                                                             int* __restrict__ blockOff, int nb,
                                                             int* __restrict__ rowptr_last) {
    __shared__ int lds[256];
    int t = threadIdx.x;
    int v = (t < nb) ? blockSum[t] : 0;
    lds[t] = v;
    __syncthreads();
    for (int off = 1; off < 256; off <<= 1) {
        int u = (t >= off) ? lds[t - off] : 0;
        __syncthreads();
        lds[t] += u;
        __syncthreads();
    }
    if (t < nb) blockOff[t] = lds[t] - v;  // exclusive
    if (t == 255) *rowptr_last = lds[255];
}

__global__ __launch_bounds__(256) void block_scan_kernel(const int* deg,
                                                         const int* __restrict__ blockOff,
                                                         int* __restrict__ row_ptr,
                                                         int* cursor, int n) {
    __shared__ int lds[256];
    int t = threadIdx.x;
    int i = blockIdx.x * 256 + t;
    int v = (i < n) ? deg[i] : 0;
    lds[t] = v;
    __syncthreads();
    for (int off = 1; off < 256; off <<= 1) {
        int u = (t >= off) ? lds[t - off] : 0;
        __syncthreads();
        lds[t] += u;
        __syncthreads();
    }
    if (i < n) {
        int ex = blockOff[blockIdx.x] + lds[t] - v;
        row_ptr[i] = ex;
        cursor[i] = ex;
    }
}

__global__ void fill_csr_kernel(const int* __restrict__ ei, const float* __restrict__ ew,
                                int* __restrict__ cursor, int2* __restrict__ csr_sw, int E) {
    int e = blockIdx.x * blockDim.x + threadIdx.x;
    if (e >= E) return;
    int d = ei[E + e];
    int s = ei[e];
    if ((unsigned)d >= (unsigned)NN || (unsigned)s >= (unsigned)NN) return;
    int pos = atomicAdd(&cursor[d], 1);
    if (pos < E) csr_sw[pos] = make_int2(s, __float_as_int(ew[e]));
}

// ---------------- weight prep: transpose + hi/lo bf16 split, PRE-SWIZZLED ----------------
__global__ void wsplit_kernel(const float* __restrict__ w, u16* __restrict__ hiT,
                              u16* __restrict__ loT, int din, int dout) {
    int i = blockIdx.x * 256 + threadIdx.x;
    if (i >= din * dout) return;
    int k = i / dout, n = i - k * dout;
    float v = w[i];
    u16 h = f2bf(v);
    size_t o = (size_t)n * din + swz(k, n);
    hiT[o] = h;
    loT[o] = f2bf(v - bf2f(h));
}

// w1_2 (256x40) -> padded transposed [64][256], pre-swizzled
__global__ void wsplit_pad_kernel(const float* __restrict__ w, u16* __restrict__ hiT,
                                  u16* __restrict__ loT) {
    int i = blockIdx.x * 256 + threadIdx.x;
    if (i >= 64 * 256) return;
    int n = i >> 8, k = i & 255;
    float v = (n < 40) ? w[k * 40 + n] : 0.f;
    u16 h = f2bf(v);
    size_t o = (size_t)n * 256 + swz(k, n);
    hiT[o] = h;
    loT[o] = f2bf(v - bf2f(h));
}

// ---------------- pull aggregation: out[n] = x[n] + sum_e w_e * x[src_e] ----------------
// Packed activation buffers are PRE-SWIZZLED (col ^ ((node&7)<<3) within each plane row).
//   C=128: self fp32 xf (linear), gather fp32 xf (linear), out packed swizzled [node][2][128]
//   C=256: self packed swizzled (hi+lo), gather swizzled HI plane, out packed swizzled
//   C=40 : self fp32 (linear), gather bf16 xb (linear), out fp32 (linear)
template <int C>
__global__ __launch_bounds__(256) void aggregate_kernel(
    const float* __restrict__ xf, const u16* __restrict__ xp, const u16* __restrict__ xb,
    const int* __restrict__ row_ptr, const int2* __restrict__ csw,
    float* __restrict__ outf, u16* __restrict__ outp, int n) {
    constexpr int V = (C == 128) ? 2 : 4;
    int node = blockIdx.x * 4 + (threadIdx.x >> 6);
    if (node >= n) return;
    int lane = threadIdx.x & 63;
    if (C == 40 && lane >= 10) return;
    int col = lane * V;
    int beg = row_ptr[node], end = row_ptr[node + 1];

    float acc[V];
    // ---- self term (eps = 0), full precision ----
    if constexpr (C == 128) {
        float2 v = *(const float2*)(xf + (size_t)node * C + col);
        acc[0] = v.x; acc[1] = v.y;
    } else if constexpr (C == 256) {
        size_t b = (size_t)node * (2 * C) + swz(col, node);
        ushort4 h = *(const ushort4*)(xp + b);
        ushort4 l = *(const ushort4*)(xp + b + C);
        acc[0] = bf2f(h.x) + bf2f(l.x); acc[1] = bf2f(h.y) + bf2f(l.y);
        acc[2] = bf2f(h.z) + bf2f(l.z); acc[3] = bf2f(h.w) + bf2f(l.w);
    } else {
        float4 v = *(const float4*)(xf + (size_t)node * C + col);
        acc[0] = v.x; acc[1] = v.y; acc[2] = v.z; acc[3] = v.w;
    }

    // ---- 4x-unrolled edge loop: batch loads first, then FMA ----
    int e = beg;
    for (; e + 4 <= end; e += 4) {
        int2 sw[4];
#pragma unroll
        for (int u = 0; u < 4; u++) sw[u] = csw[e + u];
        if constexpr (C == 128) {
            float2 T[4];
#pragma unroll
            for (int u = 0; u < 4; u++) T[u] = *(const float2*)(xf + (size_t)sw[u].x * C + col);
#pragma unroll
            for (int u = 0; u < 4; u++) {
                float w = __int_as_float(sw[u].y);
                acc[0] = fmaf(w, T[u].x, acc[0]);
                acc[1] = fmaf(w, T[u].y, acc[1]);
            }
        } else if constexpr (C == 256) {
            ushort4 H[4];
#pragma unroll
            for (int u = 0; u < 4; u++) {
                int s = sw[u].x;
                H[u] = *(const ushort4*)(xp + (size_t)s * (2 * C) + swz(col, s));
            }
#pragma unroll
            for (int u = 0; u < 4; u++) {
                float w = __int_as_float(sw[u].y);
                acc[0] = fmaf(w, bf2f(H[u].x), acc[0]);
                acc[1] = fmaf(w, bf2f(H[u].y), acc[1]);
                acc[2] = fmaf(w, bf2f(H[u].z), acc[2]);
                acc[3] = fmaf(w, bf2f(H[u].w), acc[3]);
            }
        } else {
            ushort4 H[4];
#pragma unroll
            for (int u = 0; u < 4; u++) H[u] = *(const ushort4*)(xb + (size_t)sw[u].x * C + col);
#pragma unroll
            for (int u = 0; u < 4; u++) {
                float w = __int_as_float(sw[u].y);
                acc[0] = fmaf(w, bf2f(H[u].x), acc[0]);
                acc[1] = fmaf(w, bf2f(H[u].y), acc[1]);
                acc[2] = fmaf(w, bf2f(H[u].z), acc[2]);
                acc[3] = fmaf(w, bf2f(H[u].w), acc[3]);
            }
        }
    }
    for (; e < end; ++e) {
        int2 sw = csw[e];
        float w = __int_as_float(sw.y);
        if constexpr (C == 128) {
            float2 v = *(const float2*)(xf + (size_t)sw.x * C + col);
            acc[0] = fmaf(w, v.x, acc[0]); acc[1] = fmaf(w, v.y, acc[1]);
        } else if constexpr (C == 256) {
            ushort4 h = *(const ushort4*)(xp + (size_t)sw.x * (2 * C) + swz(col, sw.x));
            acc[0] = fmaf(w, bf2f(h.x), acc[0]); acc[1] = fmaf(w, bf2f(h.y), acc[1]);
            acc[2] = fmaf(w, bf2f(h.z), acc[2]); acc[3] = fmaf(w, bf2f(h.w), acc[3]);
        } else {
            ushort4 h = *(const ushort4*)(xb + (size_t)sw.x * C + col);
            acc[0] = fmaf(w, bf2f(h.x), acc[0]); acc[1] = fmaf(w, bf2f(h.y), acc[1]);
            acc[2] = fmaf(w, bf2f(h.z), acc[2]); acc[3] = fmaf(w, bf2f(h.w), acc[3]);
        }
    }

    // ---- store (packed outputs pre-swizzled) ----
    if constexpr (C == 128) {
        size_t ob = (size_t)node * (2 * C) + swz(col, node);
        ushort2 h, l;
        h.x = f2bf(acc[0]); l.x = f2bf(acc[0] - bf2f(h.x));
        h.y = f2bf(acc[1]); l.y = f2bf(acc[1] - bf2f(h.y));
        *(ushort2*)(outp + ob) = h;
        *(ushort2*)(outp + ob + C) = l;
    } else if constexpr (C == 256) {
        size_t ob = (size_t)node * (2 * C) + swz(col, node);
        ushort4 h, l;
        h.x = f2bf(acc[0]); l.x = f2bf(acc[0] - bf2f(h.x));
        h.y = f2bf(acc[1]); l.y = f2bf(acc[1] - bf2f(h.y));
        h.z = f2bf(acc[2]); l.z = f2bf(acc[2] - bf2f(h.z));
        h.w = f2bf(acc[3]); l.w = f2bf(acc[3] - bf2f(h.w));
        *(ushort4*)(outp + ob) = h;
        *(ushort4*)(outp + ob + C) = l;
    } else {
        size_t ob = (size_t)node * C + col;
        *(float4*)(outf + ob) = make_float4(acc[0], acc[1], acc[2], acc[3]);
    }
}

// ---------------- split-bf16 MFMA GEMM: BK=64, global_load_lds staging ----------------
// A: (hi,lo) bf16 pre-swizzled, row stride LDA (Alo = Ahi + C).  B: (hi,lo) pre-swizzled [N][K].
// LDS is LINEAR (gload_lds dest); swizzle realized by pre-swizzled source + XOR on ds_read.
// EPI: 0 none, 1 bias+relu, 2 bias+BN+relu.
// OUTHL: 0 fp32 linear; 1 packed (hi,lo) PRE-SWIZZLED; 2 fp32 linear + bf16 copy linear.
template <int BN_, int EPI, int OUTHL>
__global__ __launch_bounds__(256, 2) void gemm_mfma_kernel(
    const u16* __restrict__ Ahi, const u16* __restrict__ Alo,
    const u16* __restrict__ Bhi, const u16* __restrict__ Blo,
    float* __restrict__ outf, u16* __restrict__ outhi, u16* __restrict__ outlo,
    int M, int K, int LDA, int LDC, int NSTORE,
    const float* __restrict__ bias,
    const float* __restrict__ bng, const float* __restrict__ bnb,
    const float* __restrict__ bnm, const float* __restrict__ bnv) {
    constexpr int WGN = (BN_ == 128) ? 2 : 1;
    constexpr int WGM = 4 / WGN;
    constexpr int WTM = 128 / WGM;  // wave tile M: 64 or 32
    constexpr int MF = WTM / 16;    // 4 or 2
    constexpr int NF = 4;           // wave tile N = 64
    __shared__ __attribute__((aligned(16))) u16 LA[2 * 128 * 64];
    __shared__ __attribute__((aligned(16))) u16 LB[2 * BN_ * 64];

    const int tid = threadIdx.x;
    const int lane = tid & 63;
    const int wid = tid >> 6;
    const int wm = wid / WGN, wn = wid % WGN;
    const int m0 = blockIdx.x * 128, n0 = blockIdx.y * BN_;
    const int ln = lane & 15, l4 = lane >> 4;

    f32x4 acc[MF][NF];
#pragma unroll
    for (int mi = 0; mi < MF; mi++)
#pragma unroll
        for (int ni = 0; ni < NF; ni++) acc[mi][ni] = (f32x4){0.f, 0.f, 0.f, 0.f};

    for (int k0 = 0; k0 < K; k0 += 64) {
        // stage A: 2048 16B chunks [plane][row][c16], linear LDS via gload_lds
#pragma unroll
        for (int rep = 0; rep < 8; rep++) {
            int idx = rep * 256 + tid;
            int plane = idx >> 10;
            int rc = idx & 1023;
            int row = rc >> 3, c16 = rc & 7;
            const u16* src = plane ? Alo : Ahi;
            int gm = m0 + row;
            if (gm > M - 1) gm = M - 1;
            gload16(src + (size_t)gm * LDA + k0 + c16 * 8, &LA[(size_t)(idx - lane) * 8]);
        }
        // stage B: BN_*16 chunks
#pragma unroll
        for (int rep = 0; rep < BN_ / 16; rep++) {
            int idx = rep * 256 + tid;
            int plane = idx / (BN_ * 8);
            int rc = idx % (BN_ * 8);
            int row = rc >> 3, c16 = rc & 7;
            const u16* src = plane ? Blo : Bhi;
            gload16(src + (size_t)(n0 + row) * K + k0 + c16 * 8, &LB[(size_t)(idx - lane) * 8]);
        }
        asm volatile("s_waitcnt vmcnt(0)" ::: "memory");
        __syncthreads();

#pragma unroll
        for (int kk = 0; kk < 2; kk++) {
            bf16x8 ah[MF], al[MF], bh[NF], bl[NF];
#pragma unroll
            for (int mi = 0; mi < MF; mi++) {
                int row = wm * WTM + mi * 16 + ln;
                int slot = (kk * 4 + l4) ^ (row & 7);
                ah[mi] = *(const bf16x8*)&LA[row * 64 + slot * 8];
                al[mi] = *(const bf16x8*)&LA[8192 + row * 64 + slot * 8];
            }
#pragma unroll
            for (int ni = 0; ni < NF; ni++) {
                int row = wn * 64 + ni * 16 + ln;
                int slot = (kk * 4 + l4) ^ (row & 7);
                bh[ni] = *(const bf16x8*)&LB[row * 64 + slot * 8];
                bl[ni] = *(const bf16x8*)&LB[BN_ * 64 + row * 64 + slot * 8];
            }
#pragma unroll
            for (int mi = 0; mi < MF; mi++)
#pragma unroll
                for (int ni = 0; ni < NF; ni++) {
                    acc[mi][ni] = __builtin_amdgcn_mfma_f32_16x16x32_bf16(ah[mi], bh[ni], acc[mi][ni], 0, 0, 0);
                    acc[mi][ni] = __builtin_amdgcn_mfma_f32_16x16x32_bf16(ah[mi], bl[ni], acc[mi][ni], 0, 0, 0);
                    acc[mi][ni] = __builtin_amdgcn_mfma_f32_16x16x32_bf16(al[mi], bh[ni], acc[mi][ni], 0, 0, 0);
                }
        }
        __syncthreads();
    }

    // epilogue: C/D layout col=lane&15, row=(lane>>4)*4+reg
#pragma unroll
    for (int ni = 0; ni < NF; ni++) {
        int c = n0 + wn * 64 + ni * 16 + ln;
        float bb = 0.f, sc = 1.f, sh = 0.f;
        if constexpr (EPI >= 1) bb = bias[c];
        if constexpr (EPI == 2) {
            float s = bng[c] * rsqrtf(bnv[c] + BN_EPS);
            sc = s;
            sh = bnb[c] - bnm[c] * s;
        }
        bool cok = (c < NSTORE);
#pragma unroll
        for (int mi = 0; mi < MF; mi++) {
#pragma unroll
            for (int r = 0; r < 4; r++) {
                int row = m0 + wm * WTM + mi * 16 + l4 * 4 + r;
                if (row < M && cok) {
                    float v = acc[mi][ni][r] + bb;
                    if constexpr (EPI == 1) v = fmaxf(v, 0.f);
                    if constexpr (EPI == 2) v = fmaxf(fmaf(v, sc, sh), 0.f);
                    if constexpr (OUTHL == 1) {
                        size_t o = (size_t)row * LDC + swz(c, row);  // pre-swizzled for next GEMM
                        u16 h = f2bf(v);
                        outhi[o] = h;
                        outlo[o] = f2bf(v - bf2f(h));
                    } else if constexpr (OUTHL == 2) {
                        size_t o = (size_t)row * LDC + c;
                        outf[o] = v;
                        outhi[o] = f2bf(v);
                    } else {
                        outf[(size_t)row * LDC + c] = v;
                    }
                }
            }
        }
    }
}

// ---------------- tail: relu(agg + b1) @ w2 + b2 -> log_softmax ----------------
__global__ __launch_bounds__(256) void final_kernel(
    const float* __restrict__ aggp, const float* __restrict__ b1,
    const float* __restrict__ w2, const float* __restrict__ b2,
    float* __restrict__ out, int n) {
    __shared__ float sw[40 * 40];
    __shared__ float sb1[40], sb2[40];
    for (int i = threadIdx.x; i < 1600; i += 256) sw[i] = w2[i];
    if (threadIdx.x < 40) { sb1[threadIdx.x] = b1[threadIdx.x]; sb2[threadIdx.x] = b2[threadIdx.x]; }
    __syncthreads();
    int row = blockIdx.x * 256 + threadIdx.x;
    if (row >= n) return;
    const float* ar = aggp + (size_t)row * 40;
    float t[40];
#pragma unroll
    for (int k = 0; k < 40; k++) t[k] = fmaxf(ar[k] + sb1[k], 0.f);
    float y[40];
#pragma unroll
    for (int j = 0; j < 40; j++) y[j] = sb2[j];
    for (int k = 0; k < 40; k++) {
        float tk = t[k];
#pragma unroll
        for (int j = 0; j < 40; j++) y[j] = fmaf(tk, sw[k * 40 + j], y[j]);
    }
    float m = -1e30f;
#pragma unroll
    for (int j = 0; j < 40; j++) m = fmaxf(m, y[j]);
    float s = 0.f;
#pragma unroll
    for (int j = 0; j < 40; j++) s += expf(y[j] - m);
    float lse = m + logf(s);
    float* orow = out + (size_t)row * 40;
#pragma unroll
    for (int j = 0; j < 40; j++) orow[j] = y[j] - lse;
}

extern "C" void kernel_launch(void* const* d_in, const int* in_sizes, int n_in,
                              void* d_out, int out_size, void* d_ws, size_t ws_size,
                              hipStream_t stream) {
    const float* x    = (const float*)d_in[0];
    const int*   ei   = (const int*)d_in[1];  // int64 in ref -> int32 on device
    const float* ew   = (const float*)d_in[2];
    const float* w1_0 = (const float*)d_in[3],  *b1_0 = (const float*)d_in[4];
    const float* w2_0 = (const float*)d_in[5],  *b2_0 = (const float*)d_in[6];
    const float* w1_1 = (const float*)d_in[7],  *b1_1 = (const float*)d_in[8];
    const float* w2_1 = (const float*)d_in[9],  *b2_1 = (const float*)d_in[10];
    const float* w1_2 = (const float*)d_in[11], *b1_2 = (const float*)d_in[12];
    const float* w2_2 = (const float*)d_in[13], *b2_2 = (const float*)d_in[14];
    const float* bng0 = (const float*)d_in[15], *bnb0 = (const float*)d_in[16];
    const float* bnm0 = (const float*)d_in[17], *bnv0 = (const float*)d_in[18];
    const float* bng1 = (const float*)d_in[19], *bnb1 = (const float*)d_in[20];
    const float* bnm1 = (const float*)d_in[21], *bnv1 = (const float*)d_in[22];
    float* out = (float*)d_out;

    char* wsp = (char*)d_ws;
    size_t off = 0;
    auto alloc = [&](size_t bytes) -> char* {
        char* p = wsp + off;
        off += (bytes + 255) & ~(size_t)255;
        return p;
    };
    int*   cursor   = (int*)alloc((size_t)NN * sizeof(int));
    int*   row_ptr  = (int*)alloc((size_t)(NN + 1) * sizeof(int));
    int*   blockSum = (int*)alloc(256 * sizeof(int));
    int*   blockOff = (int*)alloc(256 * sizeof(int));
    int2*  csr_sw   = (int2*)alloc((size_t)NE * sizeof(int2));
    u16* bufP = (u16*)alloc((size_t)NN * 512 * sizeof(u16));  // packed [node][2][256]
    u16* bufQ = (u16*)alloc((size_t)NN * 512 * sizeof(u16));
    u16* w10h = (u16*)alloc(128 * 256 * 2); u16* w10l = (u16*)alloc(128 * 256 * 2);
    u16* w20h = (u16*)alloc(256 * 256 * 2); u16* w20l = (u16*)alloc(256 * 256 * 2);
    u16* w11h = (u16*)alloc(256 * 256 * 2); u16* w11l = (u16*)alloc(256 * 256 * 2);
    u16* w21h = (u16*)alloc(256 * 256 * 2); u16* w21l = (u16*)alloc(256 * 256 * 2);
    u16* wph  = (u16*)alloc(64 * 256 * 2);  u16* wpl  = (u16*)alloc(64 * 256 * 2);

    const int NB = (NN + 255) / 256;  // 196

    // --- CSR build (parallel scan) ---
    hipMemsetAsync(cursor, 0, (size_t)NN * sizeof(int), stream);
    count_deg_kernel<<<(NE + 255) / 256, 256, 0, stream>>>(ei, cursor, NE);
    block_reduce_kernel<<<NB, 256, 0, stream>>>(cursor, blockSum, NN);
    scan_blocksums_kernel<<<1, 256, 0, stream>>>(blockSum, blockOff, NB, row_ptr + NN);
    block_scan_kernel<<<NB, 256, 0, stream>>>(cursor, blockOff, row_ptr, cursor, NN);
    fill_csr_kernel<<<(NE + 255) / 256, 256, 0, stream>>>(ei, ew, cursor, csr_sw, NE);

    // --- weight prep (pre-swizzled) ---
    wsplit_kernel<<<(128 * 256 + 255) / 256, 256, 0, stream>>>(w1_0, w10h, w10l, 128, 256);
    wsplit_kernel<<<(256 * 256 + 255) / 256, 256, 0, stream>>>(w2_0, w20h, w20l, 256, 256);
    wsplit_kernel<<<(256 * 256 + 255) / 256, 256, 0, stream>>>(w1_1, w11h, w11l, 256, 256);
    wsplit_kernel<<<(256 * 256 + 255) / 256, 256, 0, stream>>>(w2_1, w21h, w21l, 256, 256);
    wsplit_pad_kernel<<<64, 256, 0, stream>>>(w1_2, wph, wpl);

    const int aggBlocks = (NN + 3) / 4;
    dim3 gBig((NN + 127) / 128, 2);
    dim3 gSm((NN + 127) / 128, 1);

    // ---- layer 0 ----  (bufP: packed [node][2][128], LDA=256)
    aggregate_kernel<128><<<aggBlocks, 256, 0, stream>>>(
        x, nullptr, nullptr, row_ptr, csr_sw, nullptr, bufP, NN);
    gemm_mfma_kernel<128, 1, 1><<<gBig, 256, 0, stream>>>(
        bufP, bufP + 128, w10h, w10l, nullptr, bufQ, bufQ + 256, NN, 128, 256, 512, 256,
        b1_0, nullptr, nullptr, nullptr, nullptr);
    gemm_mfma_kernel<128, 2, 1><<<gBig, 256, 0, stream>>>(
        bufQ, bufQ + 256, w20h, w20l, nullptr, bufP, bufP + 256, NN, 256, 512, 512, 256,
        b2_0, bng0, bnb0, bnm0, bnv0);

    // ---- layer 1 ---- (agg gathers HI plane only)
    aggregate_kernel<256><<<aggBlocks, 256, 0, stream>>>(
        nullptr, bufP, nullptr, row_ptr, csr_sw, nullptr, bufQ, NN);
    gemm_mfma_kernel<128, 1, 1><<<gBig, 256, 0, stream>>>(
        bufQ, bufQ + 256, w11h, w11l, nullptr, bufP, bufP + 256, NN, 256, 512, 512, 256,
        b1_1, nullptr, nullptr, nullptr, nullptr);
    gemm_mfma_kernel<128, 2, 1><<<gBig, 256, 0, stream>>>(
        bufP, bufP + 256, w21h, w21l, nullptr, bufQ, bufQ + 256, NN, 256, 512, 512, 256,
        b2_1, bng1, bnb1, bnm1, bnv1);

    // ---- layer 2 (reordered: p = h @ w1_2 first, then aggregate 40 channels) ----
    float* p    = (float*)bufP;
    u16*   pbf  = bufP + 4000000;            // 8 MB offset in u16 elements
    float* aggp = (float*)bufQ;
    gemm_mfma_kernel<64, 0, 2><<<gSm, 256, 0, stream>>>(
        bufQ, bufQ + 256, wph, wpl, p, pbf, nullptr, NN, 256, 512, 40, 40,
        nullptr, nullptr, nullptr, nullptr, nullptr);
    aggregate_kernel<40><<<aggBlocks, 256, 0, stream>>>(
        p, nullptr, pbf, row_ptr, csr_sw, aggp, nullptr, NN);
    final_kernel<<<NB, 256, 0, stream>>>(aggp, b1_2, w2_2, b2_2, out, NN);
}

// Round 9
// 444.643 us; speedup vs baseline: 2.0418x; 1.1209x over previous
//
#include <hip/hip_runtime.h>
#include <cstdint>
#include <cstddef>

#define BN_EPS 1e-5f

typedef unsigned short u16;
typedef __attribute__((ext_vector_type(8))) short bf16x8;   // 8 bf16 (4 VGPRs)
typedef __attribute__((ext_vector_type(4))) float f32x4;

constexpr int NN = 50000;
constexpr int NE = 800000;

__device__ __forceinline__ u16 f2bf(float f) {
    unsigned u = __float_as_uint(f);
    return (u16)((u + 0x7fffu + ((u >> 16) & 1u)) >> 16);   // RNE
}
__device__ __forceinline__ float bf2f(u16 h) { return __uint_as_float(((unsigned)h) << 16); }

// async global->LDS 16B DMA (dest = wave-uniform base + lane*16)
__device__ __forceinline__ void gload16(const u16* g, u16* l) {
    __builtin_amdgcn_global_load_lds(
        (const __attribute__((address_space(1))) void*)g,
        (__attribute__((address_space(3))) void*)l, 16, 0, 0);
}

// u16-index XOR swizzle within a 64-u16 (128 B) group
__device__ __forceinline__ int swz(int col_u16, int row) {
    return col_u16 ^ ((row & 7) << 3);
}

// ---------------- CSR build (edge_index arrives as int32) ----------------
__global__ void count_deg_kernel(const int* __restrict__ ei, int* __restrict__ deg, int E) {
    int e = blockIdx.x * blockDim.x + threadIdx.x;
    if (e >= E) return;
    int d = ei[E + e];
    if ((unsigned)d < (unsigned)NN) atomicAdd(&deg[d], 1);
}

__global__ __launch_bounds__(256) void block_reduce_kernel(const int* __restrict__ deg,
                                                           int* __restrict__ blockSum, int n) {
    __shared__ int red[256];
    int i = blockIdx.x * 256 + threadIdx.x;
    red[threadIdx.x] = (i < n) ? deg[i] : 0;
    __syncthreads();
    for (int s = 128; s > 0; s >>= 1) {
        if (threadIdx.x < s) red[threadIdx.x] += red[threadIdx.x + s];
        __syncthreads();
    }
    if (threadIdx.x == 0) blockSum[blockIdx.x] = red[0];
}

__global__ __launch_bounds__(256) void scan_blocksums_kernel(const int* __restrict__ blockSum,
                                                             int* __restrict__ blockOff, int nb,
                                                             int* __restrict__ rowptr_last) {
    __shared__ int lds[256];
    int t = threadIdx.x;
    int v = (t < nb) ? blockSum[t] : 0;
    lds[t] = v;
    __syncthreads();
    for (int off = 1; off < 256; off <<= 1) {
        int u = (t >= off) ? lds[t - off] : 0;
        __syncthreads();
        lds[t] += u;
        __syncthreads();
    }
    if (t < nb) blockOff[t] = lds[t] - v;  // exclusive
    if (t == 255) *rowptr_last = lds[255];
}

__global__ __launch_bounds__(256) void block_scan_kernel(const int* deg,
                                                         const int* __restrict__ blockOff,
                                                         int* __restrict__ row_ptr,
                                                         int* cursor, int n) {
    __shared__ int lds[256];
    int t = threadIdx.x;
    int i = blockIdx.x * 256 + t;
    int v = (i < n) ? deg[i] : 0;
    lds[t] = v;
    __syncthreads();
    for (int off = 1; off < 256; off <<= 1) {
        int u = (t >= off) ? lds[t - off] : 0;
        __syncthreads();
        lds[t] += u;
        __syncthreads();
    }
    if (i < n) {
        int ex = blockOff[blockIdx.x] + lds[t] - v;
        row_ptr[i] = ex;
        cursor[i] = ex;
    }
}

__global__ void fill_csr_kernel(const int* __restrict__ ei, const float* __restrict__ ew,
                                int* __restrict__ cursor, int2* __restrict__ csr_sw, int E) {
    int e = blockIdx.x * blockDim.x + threadIdx.x;
    if (e >= E) return;
    int d = ei[E + e];
    int s = ei[e];
    if ((unsigned)d >= (unsigned)NN || (unsigned)s >= (unsigned)NN) return;
    int pos = atomicAdd(&cursor[d], 1);
    if (pos < E) csr_sw[pos] = make_int2(s, __float_as_int(ew[e]));
}

// ---------------- x (fp32) -> bf16, pre-swizzled [node][128] ----------------
__global__ __launch_bounds__(256) void xconvert_kernel(const float* __restrict__ x,
                                                       u16* __restrict__ xbf) {
    int i = blockIdx.x * 256 + threadIdx.x;   // NN*64 threads, 2 cols each
    if (i >= NN * 64) return;
    int node = i >> 6;
    int col = (i & 63) * 2;
    float2 v = *(const float2*)(x + (size_t)node * 128 + col);
    ushort2 h;
    h.x = f2bf(v.x);
    h.y = f2bf(v.y);
    *(ushort2*)(xbf + (size_t)node * 128 + swz(col, node)) = h;
}

// ---------------- weight prep: transpose + hi/lo split, pre-swizzled ----------------
__global__ void wsplit_kernel(const float* __restrict__ w, u16* __restrict__ hiT,
                              u16* __restrict__ loT, int din, int dout) {
    int i = blockIdx.x * 256 + threadIdx.x;
    if (i >= din * dout) return;
    int k = i / dout, n = i - k * dout;
    float v = w[i];
    u16 h = f2bf(v);
    size_t o = (size_t)n * din + swz(k, n);
    hiT[o] = h;
    loT[o] = f2bf(v - bf2f(h));
}

// w2 with BN fold: w' = w * sc[n]
__global__ void wsplit_bn_kernel(const float* __restrict__ w, const float* __restrict__ g,
                                 const float* __restrict__ vv, u16* __restrict__ hiT,
                                 u16* __restrict__ loT, int din, int dout) {
    int i = blockIdx.x * 256 + threadIdx.x;
    if (i >= din * dout) return;
    int k = i / dout, n = i - k * dout;
    float sc = g[n] * rsqrtf(vv[n] + BN_EPS);
    float v = w[i] * sc;
    u16 h = f2bf(v);
    size_t o = (size_t)n * din + swz(k, n);
    hiT[o] = h;
    loT[o] = f2bf(v - bf2f(h));
}

// folded bias: b' = (b2 - m)*sc + beta
__global__ void bias_fold_kernel(const float* __restrict__ b2, const float* __restrict__ g,
                                 const float* __restrict__ bb, const float* __restrict__ m,
                                 const float* __restrict__ vv, float* __restrict__ outb) {
    int n = threadIdx.x;  // 256
    float sc = g[n] * rsqrtf(vv[n] + BN_EPS);
    outb[n] = (b2[n] - m[n]) * sc + bb[n];
}

// w1_2 (256x40) -> padded transposed [64][256], pre-swizzled
__global__ void wsplit_pad_kernel(const float* __restrict__ w, u16* __restrict__ hiT,
                                  u16* __restrict__ loT) {
    int i = blockIdx.x * 256 + threadIdx.x;
    if (i >= 64 * 256) return;
    int n = i >> 8, k = i & 255;
    float v = (n < 40) ? w[k * 40 + n] : 0.f;
    u16 h = f2bf(v);
    size_t o = (size_t)n * 256 + swz(k, n);
    hiT[o] = h;
    loT[o] = f2bf(v - bf2f(h));
}

// ---------------- pull aggregation: out[n] = x[n] + sum_e w_e * x[src_e] ----------------
//   C=128: self/gather/out bf16 pre-swizzled [node][128], V=2
//   C=256: self/gather/out bf16 pre-swizzled [node][256], V=4
//   C=40 : self fp32 linear, gather bf16 linear, out fp32 linear, V=4 (lanes<10)
template <int C>
__global__ __launch_bounds__(256) void aggregate_kernel(
    const float* __restrict__ xf, const u16* __restrict__ xp, const u16* __restrict__ xb,
    const int* __restrict__ row_ptr, const int2* __restrict__ csw,
    float* __restrict__ outf, u16* __restrict__ outp, int n) {
    constexpr int V = (C == 128) ? 2 : 4;
    int node = blockIdx.x * 4 + (threadIdx.x >> 6);
    if (node >= n) return;
    int lane = threadIdx.x & 63;
    if (C == 40 && lane >= 10) return;
    int col = lane * V;
    int beg = row_ptr[node], end = row_ptr[node + 1];

    float acc[V];
    // ---- self term (eps = 0) ----
    if constexpr (C == 128) {
        ushort2 h = *(const ushort2*)(xp + (size_t)node * C + swz(col, node));
        acc[0] = bf2f(h.x); acc[1] = bf2f(h.y);
    } else if constexpr (C == 256) {
        ushort4 h = *(const ushort4*)(xp + (size_t)node * C + swz(col, node));
        acc[0] = bf2f(h.x); acc[1] = bf2f(h.y); acc[2] = bf2f(h.z); acc[3] = bf2f(h.w);
    } else {
        float4 v = *(const float4*)(xf + (size_t)node * C + col);
        acc[0] = v.x; acc[1] = v.y; acc[2] = v.z; acc[3] = v.w;
    }

    // ---- 4x-unrolled edge loop: batch loads, then FMA ----
    int e = beg;
    for (; e + 4 <= end; e += 4) {
        int2 sw[4];
#pragma unroll
        for (int u = 0; u < 4; u++) sw[u] = csw[e + u];
        if constexpr (C == 128) {
            ushort2 H[4];
#pragma unroll
            for (int u = 0; u < 4; u++) {
                int s = sw[u].x;
                H[u] = *(const ushort2*)(xp + (size_t)s * C + swz(col, s));
            }
#pragma unroll
            for (int u = 0; u < 4; u++) {
                float w = __int_as_float(sw[u].y);
                acc[0] = fmaf(w, bf2f(H[u].x), acc[0]);
                acc[1] = fmaf(w, bf2f(H[u].y), acc[1]);
            }
        } else if constexpr (C == 256) {
            ushort4 H[4];
#pragma unroll
            for (int u = 0; u < 4; u++) {
                int s = sw[u].x;
                H[u] = *(const ushort4*)(xp + (size_t)s * C + swz(col, s));
            }
#pragma unroll
            for (int u = 0; u < 4; u++) {
                float w = __int_as_float(sw[u].y);
                acc[0] = fmaf(w, bf2f(H[u].x), acc[0]);
                acc[1] = fmaf(w, bf2f(H[u].y), acc[1]);
                acc[2] = fmaf(w, bf2f(H[u].z), acc[2]);
                acc[3] = fmaf(w, bf2f(H[u].w), acc[3]);
            }
        } else {
            ushort4 H[4];
#pragma unroll
            for (int u = 0; u < 4; u++) H[u] = *(const ushort4*)(xb + (size_t)sw[u].x * C + col);
#pragma unroll
            for (int u = 0; u < 4; u++) {
                float w = __int_as_float(sw[u].y);
                acc[0] = fmaf(w, bf2f(H[u].x), acc[0]);
                acc[1] = fmaf(w, bf2f(H[u].y), acc[1]);
                acc[2] = fmaf(w, bf2f(H[u].z), acc[2]);
                acc[3] = fmaf(w, bf2f(H[u].w), acc[3]);
            }
        }
    }
    for (; e < end; ++e) {
        int2 sw = csw[e];
        float w = __int_as_float(sw.y);
        if constexpr (C == 128) {
            ushort2 h = *(const ushort2*)(xp + (size_t)sw.x * C + swz(col, sw.x));
            acc[0] = fmaf(w, bf2f(h.x), acc[0]); acc[1] = fmaf(w, bf2f(h.y), acc[1]);
        } else if constexpr (C == 256) {
            ushort4 h = *(const ushort4*)(xp + (size_t)sw.x * C + swz(col, sw.x));
            acc[0] = fmaf(w, bf2f(h.x), acc[0]); acc[1] = fmaf(w, bf2f(h.y), acc[1]);
            acc[2] = fmaf(w, bf2f(h.z), acc[2]); acc[3] = fmaf(w, bf2f(h.w), acc[3]);
        } else {
            ushort4 h = *(const ushort4*)(xb + (size_t)sw.x * C + col);
            acc[0] = fmaf(w, bf2f(h.x), acc[0]); acc[1] = fmaf(w, bf2f(h.y), acc[1]);
            acc[2] = fmaf(w, bf2f(h.z), acc[2]); acc[3] = fmaf(w, bf2f(h.w), acc[3]);
        }
    }

    // ---- store ----
    if constexpr (C == 128) {
        ushort2 h;
        h.x = f2bf(acc[0]); h.y = f2bf(acc[1]);
        *(ushort2*)(outp + (size_t)node * C + swz(col, node)) = h;
    } else if constexpr (C == 256) {
        ushort4 h;
        h.x = f2bf(acc[0]); h.y = f2bf(acc[1]); h.z = f2bf(acc[2]); h.w = f2bf(acc[3]);
        *(ushort4*)(outp + (size_t)node * C + swz(col, node)) = h;
    } else {
        *(float4*)(outf + (size_t)node * C + col) = make_float4(acc[0], acc[1], acc[2], acc[3]);
    }
}

// ---------------- bf16-A x split-B MFMA GEMM: BK=64, global_load_lds staging ----------------
// A: bf16 pre-swizzled [M][LDA].  B: (hi,lo) bf16 pre-swizzled [N][K].
// 2 MFMA passes: A*Bhi + A*Blo. EPI: 0 none, 1 bias+relu.
// OUTHL: 0 fp32 linear; 1 bf16 pre-swizzled; 2 fp32 linear + bf16 copy linear.
template <int BN_, int EPI, int OUTHL>
__global__ __launch_bounds__(256, 3) void gemm_mfma_kernel(
    const u16* __restrict__ Ahi,
    const u16* __restrict__ Bhi, const u16* __restrict__ Blo,
    float* __restrict__ outf, u16* __restrict__ outhi,
    int M, int K, int LDA, int LDC, int NSTORE,
    const float* __restrict__ bias) {
    constexpr int WGN = (BN_ == 128) ? 2 : 1;
    constexpr int WGM = 4 / WGN;
    constexpr int WTM = 128 / WGM;  // wave tile M: 64 or 32
    constexpr int MF = WTM / 16;    // 4 or 2
    constexpr int NF = 4;           // wave tile N = 64
    __shared__ __attribute__((aligned(16))) u16 LA[128 * 64];
    __shared__ __attribute__((aligned(16))) u16 LB[2 * BN_ * 64];

    const int tid = threadIdx.x;
    const int lane = tid & 63;
    const int wid = tid >> 6;
    const int wm = wid / WGN, wn = wid % WGN;
    const int m0 = blockIdx.x * 128, n0 = blockIdx.y * BN_;
    const int ln = lane & 15, l4 = lane >> 4;

    f32x4 acc[MF][NF];
#pragma unroll
    for (int mi = 0; mi < MF; mi++)
#pragma unroll
        for (int ni = 0; ni < NF; ni++) acc[mi][ni] = (f32x4){0.f, 0.f, 0.f, 0.f};

    for (int k0 = 0; k0 < K; k0 += 64) {
        // stage A: 1024 16B chunks [row][c16], 4 reps
#pragma unroll
        for (int rep = 0; rep < 4; rep++) {
            int idx = rep * 256 + tid;
            int row = idx >> 3, c16 = idx & 7;
            int gm = m0 + row;
            if (gm > M - 1) gm = M - 1;
            gload16(Ahi + (size_t)gm * LDA + k0 + c16 * 8, &LA[(size_t)(idx - lane) * 8]);
        }
        // stage B: BN_*16 chunks [plane][row][c16]
#pragma unroll
        for (int rep = 0; rep < BN_ / 16; rep++) {
            int idx = rep * 256 + tid;
            int plane = idx / (BN_ * 8);
            int rc = idx % (BN_ * 8);
            int row = rc >> 3, c16 = rc & 7;
            const u16* src = plane ? Blo : Bhi;
            gload16(src + (size_t)(n0 + row) * K + k0 + c16 * 8, &LB[(size_t)(idx - lane) * 8]);
        }
        asm volatile("s_waitcnt vmcnt(0)" ::: "memory");
        __syncthreads();

#pragma unroll
        for (int kk = 0; kk < 2; kk++) {
            bf16x8 ah[MF], bh[NF], bl[NF];
#pragma unroll
            for (int mi = 0; mi < MF; mi++) {
                int row = wm * WTM + mi * 16 + ln;
                int slot = (kk * 4 + l4) ^ (row & 7);
                ah[mi] = *(const bf16x8*)&LA[row * 64 + slot * 8];
            }
#pragma unroll
            for (int ni = 0; ni < NF; ni++) {
                int row = wn * 64 + ni * 16 + ln;
                int slot = (kk * 4 + l4) ^ (row & 7);
                bh[ni] = *(const bf16x8*)&LB[row * 64 + slot * 8];
                bl[ni] = *(const bf16x8*)&LB[BN_ * 64 + row * 64 + slot * 8];
            }
#pragma unroll
            for (int mi = 0; mi < MF; mi++)
#pragma unroll
                for (int ni = 0; ni < NF; ni++) {
                    acc[mi][ni] = __builtin_amdgcn_mfma_f32_16x16x32_bf16(ah[mi], bh[ni], acc[mi][ni], 0, 0, 0);
                    acc[mi][ni] = __builtin_amdgcn_mfma_f32_16x16x32_bf16(ah[mi], bl[ni], acc[mi][ni], 0, 0, 0);
                }
        }
        __syncthreads();
    }

    // epilogue: C/D layout col=lane&15, row=(lane>>4)*4+reg
#pragma unroll
    for (int ni = 0; ni < NF; ni++) {
        int c = n0 + wn * 64 + ni * 16 + ln;
        float bb = 0.f;
        if constexpr (EPI == 1) bb = bias[c];
        bool cok = (c < NSTORE);
#pragma unroll
        for (int mi = 0; mi < MF; mi++) {
#pragma unroll
            for (int r = 0; r < 4; r++) {
                int row = m0 + wm * WTM + mi * 16 + l4 * 4 + r;
                if (row < M && cok) {
                    float v = acc[mi][ni][r] + bb;
                    if constexpr (EPI == 1) v = fmaxf(v, 0.f);
                    if constexpr (OUTHL == 1) {
                        outhi[(size_t)row * LDC + swz(c, row)] = f2bf(v);
                    } else if constexpr (OUTHL == 2) {
                        size_t o = (size_t)row * LDC + c;
                        outf[o] = v;
                        outhi[o] = f2bf(v);
                    } else {
                        outf[(size_t)row * LDC + c] = v;
                    }
                }
            }
        }
    }
}

// ---------------- tail: relu(agg + b1) @ w2 + b2 -> log_softmax ----------------
__global__ __launch_bounds__(256) void final_kernel(
    const float* __restrict__ aggp, const float* __restrict__ b1,
    const float* __restrict__ w2, const float* __restrict__ b2,
    float* __restrict__ out, int n) {
    __shared__ float sw[40 * 40];
    __shared__ float sb1[40], sb2[40];
    for (int i = threadIdx.x; i < 1600; i += 256) sw[i] = w2[i];
    if (threadIdx.x < 40) { sb1[threadIdx.x] = b1[threadIdx.x]; sb2[threadIdx.x] = b2[threadIdx.x]; }
    __syncthreads();
    int row = blockIdx.x * 256 + threadIdx.x;
    if (row >= n) return;
    const float* ar = aggp + (size_t)row * 40;
    float t[40];
#pragma unroll
    for (int k = 0; k < 40; k++) t[k] = fmaxf(ar[k] + sb1[k], 0.f);
    float y[40];
#pragma unroll
    for (int j = 0; j < 40; j++) y[j] = sb2[j];
    for (int k = 0; k < 40; k++) {
        float tk = t[k];
#pragma unroll
        for (int j = 0; j < 40; j++) y[j] = fmaf(tk, sw[k * 40 + j], y[j]);
    }
    float m = -1e30f;
#pragma unroll
    for (int j = 0; j < 40; j++) m = fmaxf(m, y[j]);
    float s = 0.f;
#pragma unroll
    for (int j = 0; j < 40; j++) s += expf(y[j] - m);
    float lse = m + logf(s);
    float* orow = out + (size_t)row * 40;
#pragma unroll
    for (int j = 0; j < 40; j++) orow[j] = y[j] - lse;
}

extern "C" void kernel_launch(void* const* d_in, const int* in_sizes, int n_in,
                              void* d_out, int out_size, void* d_ws, size_t ws_size,
                              hipStream_t stream) {
    const float* x    = (const float*)d_in[0];
    const int*   ei   = (const int*)d_in[1];  // int64 in ref -> int32 on device
    const float* ew   = (const float*)d_in[2];
    const float* w1_0 = (const float*)d_in[3],  *b1_0 = (const float*)d_in[4];
    const float* w2_0 = (const float*)d_in[5],  *b2_0 = (const float*)d_in[6];
    const float* w1_1 = (const float*)d_in[7],  *b1_1 = (const float*)d_in[8];
    const float* w2_1 = (const float*)d_in[9],  *b2_1 = (const float*)d_in[10];
    const float* w1_2 = (const float*)d_in[11], *b1_2 = (const float*)d_in[12];
    const float* w2_2 = (const float*)d_in[13], *b2_2 = (const float*)d_in[14];
    const float* bng0 = (const float*)d_in[15], *bnb0 = (const float*)d_in[16];
    const float* bnm0 = (const float*)d_in[17], *bnv0 = (const float*)d_in[18];
    const float* bng1 = (const float*)d_in[19], *bnb1 = (const float*)d_in[20];
    const float* bnm1 = (const float*)d_in[21], *bnv1 = (const float*)d_in[22];
    float* out = (float*)d_out;

    char* wsp = (char*)d_ws;
    size_t off = 0;
    auto alloc = [&](size_t bytes) -> char* {
        char* p = wsp + off;
        off += (bytes + 255) & ~(size_t)255;
        return p;
    };
    int*   cursor   = (int*)alloc((size_t)NN * sizeof(int));
    int*   row_ptr  = (int*)alloc((size_t)(NN + 1) * sizeof(int));
    int*   blockSum = (int*)alloc(256 * sizeof(int));
    int*   blockOff = (int*)alloc(256 * sizeof(int));
    int2*  csr_sw   = (int2*)alloc((size_t)NE * sizeof(int2));
    u16* xbf   = (u16*)alloc((size_t)NN * 128 * sizeof(u16));   // also reused as aggp (fp32 8MB)
    u16* h0agg = (u16*)alloc((size_t)NN * 128 * sizeof(u16));
    u16* bufA  = (u16*)alloc((size_t)NN * 256 * sizeof(u16));
    u16* bufB  = (u16*)alloc((size_t)NN * 256 * sizeof(u16));
    u16* w10h = (u16*)alloc(128 * 256 * 2); u16* w10l = (u16*)alloc(128 * 256 * 2);
    u16* w20h = (u16*)alloc(256 * 256 * 2); u16* w20l = (u16*)alloc(256 * 256 * 2);
    u16* w11h = (u16*)alloc(256 * 256 * 2); u16* w11l = (u16*)alloc(256 * 256 * 2);
    u16* w21h = (u16*)alloc(256 * 256 * 2); u16* w21l = (u16*)alloc(256 * 256 * 2);
    u16* wph  = (u16*)alloc(64 * 256 * 2);  u16* wpl  = (u16*)alloc(64 * 256 * 2);
    float* bf0 = (float*)alloc(256 * sizeof(float));
    float* bf1 = (float*)alloc(256 * sizeof(float));

    const int NB = (NN + 255) / 256;  // 196

    // --- CSR build (parallel scan) ---
    hipMemsetAsync(cursor, 0, (size_t)NN * sizeof(int), stream);
    count_deg_kernel<<<(NE + 255) / 256, 256, 0, stream>>>(ei, cursor, NE);
    block_reduce_kernel<<<NB, 256, 0, stream>>>(cursor, blockSum, NN);
    scan_blocksums_kernel<<<1, 256, 0, stream>>>(blockSum, blockOff, NB, row_ptr + NN);
    block_scan_kernel<<<NB, 256, 0, stream>>>(cursor, blockOff, row_ptr, cursor, NN);
    fill_csr_kernel<<<(NE + 255) / 256, 256, 0, stream>>>(ei, ew, cursor, csr_sw, NE);

    // --- input convert + weight prep (pre-swizzled; BN folded into w2/b2) ---
    xconvert_kernel<<<(NN * 64 + 255) / 256, 256, 0, stream>>>(x, xbf);
    wsplit_kernel<<<(128 * 256 + 255) / 256, 256, 0, stream>>>(w1_0, w10h, w10l, 128, 256);
    wsplit_bn_kernel<<<(256 * 256 + 255) / 256, 256, 0, stream>>>(w2_0, bng0, bnv0, w20h, w20l, 256, 256);
    wsplit_kernel<<<(256 * 256 + 255) / 256, 256, 0, stream>>>(w1_1, w11h, w11l, 256, 256);
    wsplit_bn_kernel<<<(256 * 256 + 255) / 256, 256, 0, stream>>>(w2_1, bng1, bnv1, w21h, w21l, 256, 256);
    wsplit_pad_kernel<<<64, 256, 0, stream>>>(w1_2, wph, wpl);
    bias_fold_kernel<<<1, 256, 0, stream>>>(b2_0, bng0, bnb0, bnm0, bnv0, bf0);
    bias_fold_kernel<<<1, 256, 0, stream>>>(b2_1, bng1, bnb1, bnm1, bnv1, bf1);

    const int aggBlocks = (NN + 3) / 4;
    dim3 gBig((NN + 127) / 128, 2);
    dim3 gSm((NN + 127) / 128, 1);

    // ---- layer 0 ----
    aggregate_kernel<128><<<aggBlocks, 256, 0, stream>>>(
        nullptr, xbf, nullptr, row_ptr, csr_sw, nullptr, h0agg, NN);
    gemm_mfma_kernel<128, 1, 1><<<gBig, 256, 0, stream>>>(
        h0agg, w10h, w10l, nullptr, bufA, NN, 128, 128, 256, 256, b1_0);
    gemm_mfma_kernel<128, 1, 1><<<gBig, 256, 0, stream>>>(
        bufA, w20h, w20l, nullptr, bufB, NN, 256, 256, 256, 256, bf0);

    // ---- layer 1 ----
    aggregate_kernel<256><<<aggBlocks, 256, 0, stream>>>(
        nullptr, bufB, nullptr, row_ptr, csr_sw, nullptr, bufA, NN);
    gemm_mfma_kernel<128, 1, 1><<<gBig, 256, 0, stream>>>(
        bufA, w11h, w11l, nullptr, bufB, NN, 256, 256, 256, 256, b1_1);
    gemm_mfma_kernel<128, 1, 1><<<gBig, 256, 0, stream>>>(
        bufB, w21h, w21l, nullptr, bufA, NN, 256, 256, 256, 256, bf1);

    // ---- layer 2 (reordered: p = h @ w1_2 first, then aggregate 40 channels) ----
    float* p    = (float*)bufB;              // bufB dead after GEMM4 read
    u16*   pbf  = bufB + 4194304;            // 8 MB offset (u16 elements)
    float* aggp = (float*)xbf;               // xbf dead after agg<128>
    gemm_mfma_kernel<64, 0, 2><<<gSm, 256, 0, stream>>>(
        bufA, wph, wpl, p, pbf, NN, 256, 256, 40, 40, nullptr);
    aggregate_kernel<40><<<aggBlocks, 256, 0, stream>>>(
        p, nullptr, pbf, row_ptr, csr_sw, aggp, nullptr, NN);
    final_kernel<<<NB, 256, 0, stream>>>(aggp, b1_2, w2_2, b2_2, out, NN);
}